// Round 1
// baseline (10428.178 us; speedup 1.0000x reference)
//
#include <hip/hip_runtime.h>
#include <cmath>

#define NTOK 32
#define DMODEL 128
#define NCIN 64
#define CPAD 264   // 256 + 8 pad: row bank-shift, keeps 16B alignment

__device__ __forceinline__ void fma16(float acc[4][4], float x0, float x1, float x2, float x3, float4 w) {
    acc[0][0] += x0*w.x; acc[0][1] += x0*w.y; acc[0][2] += x0*w.z; acc[0][3] += x0*w.w;
    acc[1][0] += x1*w.x; acc[1][1] += x1*w.y; acc[1][2] += x1*w.z; acc[1][3] += x1*w.w;
    acc[2][0] += x2*w.x; acc[2][1] += x2*w.y; acc[2][2] += x2*w.z; acc[2][3] += x2*w.w;
    acc[3][0] += x3*w.x; acc[3][1] += x3*w.y; acc[3][2] += x3*w.z; acc[3][3] += x3*w.w;
}

// One block = one batch element n (20736 total). Whole transformer in LDS.
// PASS 1: token t = H-block index, q = Wp-block index. addr h = 2t+ph, w = 2q+pw.
// PASS 2: token t = Wp-block index, q = H-block index. addr h = 2q+ph, w = 2t+pw.
template<int PASS>
__global__ __launch_bounds__(256)
void trans_kernel(const float* __restrict__ src, float* __restrict__ dst,
                  const float* __restrict__ Win,
                  const float* __restrict__ g1, const float* __restrict__ b1,
                  const float* __restrict__ Wqk, const float* __restrict__ Wv,
                  const float* __restrict__ Wout,
                  const float* __restrict__ g2, const float* __restrict__ b2,
                  const float* __restrict__ Wff1, const float* __restrict__ Wff2,
                  const float* __restrict__ Wlin)
{
    __shared__ float xs[NTOK][NCIN];      // 8 KB   input tokens
    __shared__ float A [NTOK][DMODEL];    // 16 KB  t / t2 (residual stream)
    __shared__ float Bm[NTOK][DMODEL];    // 16 KB  tn / val / ln2
    __shared__ float C [NTOK][CPAD];      // 33 KB  qk / o / ff1
    __shared__ float S [NTOK][NTOK];      // 4 KB   attention scores

    const int tid = threadIdx.x;
    const int n = blockIdx.x;
    const int q = n & 31;
    int r = n >> 5;
    const int v_ = r % 9; r /= 9;
    const int u_ = r % 9;
    const int b_ = r / 9;
    const int s_ = u_*9 + v_;
    const size_t plane = (size_t)(b_*16)*81 + s_;   // add c*81 per channel

    // ---- gather x[t][cin] ----
    for (int i = tid; i < NTOK*NCIN; i += 256) {
        const int t = i >> 6, cin = i & 63;
        const int c = cin >> 2, ph = (cin >> 1) & 1, pw = cin & 1;
        int hh, ww;
        if (PASS == 1) { hh = 2*t + ph; ww = 2*q + pw; }
        else           { hh = 2*q + ph; ww = 2*t + pw; }
        xs[t][cin] = src[(plane + (size_t)c*81)*4096 + hh*64 + ww];
    }
    __syncthreads();

    // ---- GEMM1: A = xs @ Win  (32x64 @ 64x128) ----
    {
        const int cg = (tid & 31) * 4, rg = (tid >> 5) * 4;
        float acc[4][4] = {};
        for (int k = 0; k < NCIN; ++k) {
            float4 w = *reinterpret_cast<const float4*>(Win + k*DMODEL + cg);
            fma16(acc, xs[rg][k], xs[rg+1][k], xs[rg+2][k], xs[rg+3][k], w);
        }
        for (int j = 0; j < 4; ++j)
            for (int i = 0; i < 4; ++i) A[rg+j][cg+i] = acc[j][i];
    }
    __syncthreads();

    // ---- ln1: Bm = ln(A)*g1 + b1 ----
    {
        const int row = tid >> 3, sub = tid & 7;
        float vals[16]; float sum = 0.f;
        for (int i = 0; i < 16; ++i) { vals[i] = A[row][sub*16+i]; sum += vals[i]; }
        for (int m = 1; m < 8; m <<= 1) sum += __shfl_xor(sum, m, 8);
        const float mean = sum * (1.f/128.f);
        float var = 0.f;
        for (int i = 0; i < 16; ++i) { float d = vals[i]-mean; var += d*d; }
        for (int m = 1; m < 8; m <<= 1) var += __shfl_xor(var, m, 8);
        const float rstd = rsqrtf(var*(1.f/128.f) + 1e-5f);
        for (int i = 0; i < 16; ++i) {
            const int col = sub*16+i;
            Bm[row][col] = (vals[i]-mean)*rstd*g1[col] + b1[col];
        }
    }
    __syncthreads();

    const float scale = 0.088388347648318447f;  // 1/sqrt(128)

    // ---- GEMM2: C = (Bm @ Wqk) * scale  (32x128 @ 128x256) ----
    {
        const int cg = (tid & 63) * 4, rbase = (tid >> 6) * 4;
        for (int half = 0; half < 2; ++half) {
            const int rg = rbase + half*16;
            float acc[4][4] = {};
            for (int k = 0; k < DMODEL; ++k) {
                float4 w = *reinterpret_cast<const float4*>(Wqk + k*256 + cg);
                fma16(acc, Bm[rg][k], Bm[rg+1][k], Bm[rg+2][k], Bm[rg+3][k], w);
            }
            for (int j = 0; j < 4; ++j)
                for (int i = 0; i < 4; ++i) C[rg+j][cg+i] = acc[j][i]*scale;
        }
    }
    __syncthreads();

    // ---- scores: S[i][j] = sum_d q[i][d]*k[j][d]  (q = C[:, :128], k = C[:,128:]) ----
    {
        const int i = tid >> 3, j0 = (tid & 7) * 4;
        float acc[4] = {};
        for (int d = 0; d < DMODEL; ++d) {
            const float qi = C[i][d];
            acc[0] += qi * C[j0+0][128+d];
            acc[1] += qi * C[j0+1][128+d];
            acc[2] += qi * C[j0+2][128+d];
            acc[3] += qi * C[j0+3][128+d];
        }
        for (int j = 0; j < 4; ++j) S[i][j0+j] = acc[j];
    }
    __syncthreads();

    // ---- softmax rows of S ----
    {
        const int row = tid >> 3, sub = tid & 7;
        float v4[4]; float mx = -1e30f;
        for (int i = 0; i < 4; ++i) { v4[i] = S[row][sub*4+i]; mx = fmaxf(mx, v4[i]); }
        for (int m = 1; m < 8; m <<= 1) mx = fmaxf(mx, __shfl_xor(mx, m, 8));
        float sm = 0.f;
        for (int i = 0; i < 4; ++i) { v4[i] = expf(v4[i]-mx); sm += v4[i]; }
        for (int m = 1; m < 8; m <<= 1) sm += __shfl_xor(sm, m, 8);
        const float inv = 1.f/sm;
        for (int i = 0; i < 4; ++i) S[row][sub*4+i] = v4[i]*inv;
    }
    __syncthreads();

    // ---- val: Bm = (A @ Wv) * scale  (note: from t=A, not tn) ----
    {
        const int cg = (tid & 31) * 4, rg = (tid >> 5) * 4;
        float acc[4][4] = {};
        for (int k = 0; k < DMODEL; ++k) {
            float4 w = *reinterpret_cast<const float4*>(Wv + k*DMODEL + cg);
            fma16(acc, A[rg][k], A[rg+1][k], A[rg+2][k], A[rg+3][k], w);
        }
        for (int j = 0; j < 4; ++j)
            for (int i = 0; i < 4; ++i) Bm[rg+j][cg+i] = acc[j][i]*scale;
    }
    __syncthreads();

    // ---- o: C = S @ Bm  (32x32 @ 32x128), stored into C region ----
    {
        const int cg = (tid & 31) * 4, rg = (tid >> 5) * 4;
        float acc[4][4] = {};
        for (int k = 0; k < NTOK; ++k) {
            float4 w = *reinterpret_cast<const float4*>(&Bm[k][cg]);
            fma16(acc, S[rg][k], S[rg+1][k], S[rg+2][k], S[rg+3][k], w);
        }
        for (int j = 0; j < 4; ++j)
            for (int i = 0; i < 4; ++i) C[rg+j][cg+i] = acc[j][i];
    }
    __syncthreads();

    // ---- t2: A = C(o) @ Wout + A ----
    {
        const int cg = (tid & 31) * 4, rg = (tid >> 5) * 4;
        float acc[4][4] = {};
        for (int k = 0; k < DMODEL; ++k) {
            float4 w = *reinterpret_cast<const float4*>(Wout + k*DMODEL + cg);
            fma16(acc, C[rg][k], C[rg+1][k], C[rg+2][k], C[rg+3][k], w);
        }
        for (int j = 0; j < 4; ++j)
            for (int i = 0; i < 4; ++i) A[rg+j][cg+i] += acc[j][i];
    }
    __syncthreads();

    // ---- ln2: Bm = ln(A)*g2 + b2 ----
    {
        const int row = tid >> 3, sub = tid & 7;
        float vals[16]; float sum = 0.f;
        for (int i = 0; i < 16; ++i) { vals[i] = A[row][sub*16+i]; sum += vals[i]; }
        for (int m = 1; m < 8; m <<= 1) sum += __shfl_xor(sum, m, 8);
        const float mean = sum * (1.f/128.f);
        float var = 0.f;
        for (int i = 0; i < 16; ++i) { float d = vals[i]-mean; var += d*d; }
        for (int m = 1; m < 8; m <<= 1) var += __shfl_xor(var, m, 8);
        const float rstd = rsqrtf(var*(1.f/128.f) + 1e-5f);
        for (int i = 0; i < 16; ++i) {
            const int col = sub*16+i;
            Bm[row][col] = (vals[i]-mean)*rstd*g2[col] + b2[col];
        }
    }
    __syncthreads();

    // ---- ff1: C = gelu(Bm @ Wff1)  (32x128 @ 128x256), exact gelu ----
    {
        const int cg = (tid & 63) * 4, rbase = (tid >> 6) * 4;
        for (int half = 0; half < 2; ++half) {
            const int rg = rbase + half*16;
            float acc[4][4] = {};
            for (int k = 0; k < DMODEL; ++k) {
                float4 w = *reinterpret_cast<const float4*>(Wff1 + k*256 + cg);
                fma16(acc, Bm[rg][k], Bm[rg+1][k], Bm[rg+2][k], Bm[rg+3][k], w);
            }
            for (int j = 0; j < 4; ++j)
                for (int i = 0; i < 4; ++i) {
                    const float x = acc[j][i];
                    C[rg+j][cg+i] = 0.5f*x*(1.f + erff(x*0.70710678118654752f));
                }
        }
    }
    __syncthreads();

    // ---- ff2: A = C @ Wff2 + A  (32x256 @ 256x128) ----
    {
        const int cg = (tid & 31) * 4, rg = (tid >> 5) * 4;
        float acc[4][4] = {};
        for (int k = 0; k < 256; ++k) {
            float4 w = *reinterpret_cast<const float4*>(Wff2 + k*DMODEL + cg);
            fma16(acc, C[rg][k], C[rg+1][k], C[rg+2][k], C[rg+3][k], w);
        }
        for (int j = 0; j < 4; ++j)
            for (int i = 0; i < 4; ++i) A[rg+j][cg+i] += acc[j][i];
    }
    __syncthreads();

    // ---- out: Y = A @ Wlin (128 -> 64), scatter to dst ----
    {
        const int cg = (tid & 15) * 4, rg = (tid >> 4) * 2;
        float acc[2][4] = {};
        for (int k = 0; k < DMODEL; ++k) {
            float4 w = *reinterpret_cast<const float4*>(Wlin + k*NCIN + cg);
            const float x0 = A[rg][k], x1 = A[rg+1][k];
            acc[0][0] += x0*w.x; acc[0][1] += x0*w.y; acc[0][2] += x0*w.z; acc[0][3] += x0*w.w;
            acc[1][0] += x1*w.x; acc[1][1] += x1*w.y; acc[1][2] += x1*w.z; acc[1][3] += x1*w.w;
        }
        for (int j = 0; j < 2; ++j)
            for (int i = 0; i < 4; ++i) {
                const int cin = cg+i;
                const int c = cin >> 2, ph = (cin >> 1) & 1, pw = cin & 1;
                const int t = rg + j;
                int hh, ww;
                if (PASS == 1) { hh = 2*t + ph; ww = 2*q + pw; }
                else           { hh = 2*q + ph; ww = 2*t + pw; }
                dst[(plane + (size_t)c*81)*4096 + hh*64 + ww] = acc[j][i];
            }
    }
}

// 3x3 conv, 16->16 channels, pad 1, on (b,c,s,64,64); leaky ReLU 0.2.
// SWAPW: transpose the 3x3 taps (pass-2 tensors kept in (h,w) order).
// FINAL: add shortcut (original buffer) after activation.
template<bool SWAPW, bool FINAL>
__global__ __launch_bounds__(256)
void conv_kernel(const float* __restrict__ in, float* __restrict__ out,
                 const float* __restrict__ wgt, const float* __restrict__ shortcut)
{
    __shared__ float tin[16][10][64];   // 40 KB: 16 ci x (8+2 halo rows) x 64
    __shared__ float wl[16][16][9];     // 9 KB

    const int tid = threadIdx.x;
    const int blk = blockIdx.x;          // (b*81 + s)*8 + ytile
    const int yt = blk & 7;
    const int bs = blk >> 3;
    const int s_ = bs % 81;
    const int b_ = bs / 81;
    const int y0 = yt * 8;

    for (int i = tid; i < 16*10*64; i += 256) {
        const int ci = i / 640, rem = i % 640;
        const int yy = rem >> 6, x = rem & 63;
        const int y = y0 + yy - 1;
        float vv = 0.f;
        if (y >= 0 && y < 64)
            vv = in[((size_t)(b_*16+ci)*81 + s_)*4096 + y*64 + x];
        tin[ci][yy][x] = vv;
    }
    for (int i = tid; i < 16*16*9; i += 256) {
        const int co = i / 144, rem = i % 144;
        const int ci = rem / 9, k = rem % 9;
        const int dy = k/3, dx = k%3;
        wl[co][ci][SWAPW ? (dx*3+dy) : k] = wgt[i];
    }
    __syncthreads();

    const int x = tid & 63;
    const int cog = tid >> 6;            // 4 waves, each owns 4 output channels

    float acc[4][8] = {};
    for (int ci = 0; ci < 16; ++ci) {
        float inr[10][3];
        for (int yy = 0; yy < 10; ++yy) {
            inr[yy][0] = (x > 0)  ? tin[ci][yy][x-1] : 0.f;
            inr[yy][1] = tin[ci][yy][x];
            inr[yy][2] = (x < 63) ? tin[ci][yy][x+1] : 0.f;
        }
        float wr[4][9];
        for (int j = 0; j < 4; ++j)
            for (int k = 0; k < 9; ++k) wr[j][k] = wl[cog*4+j][ci][k];
        for (int j = 0; j < 4; ++j)
            for (int dy = 0; dy < 3; ++dy)
                for (int dx = 0; dx < 3; ++dx) {
                    const float w = wr[j][dy*3+dx];
                    for (int yy = 0; yy < 8; ++yy)
                        acc[j][yy] += inr[yy+dy][dx] * w;
                }
    }

    for (int j = 0; j < 4; ++j) {
        const int co = cog*4 + j;
        const size_t base = ((size_t)(b_*16+co)*81 + s_)*4096;
        for (int yy = 0; yy < 8; ++yy) {
            float vv = acc[j][yy];
            vv = (vv >= 0.f) ? vv : 0.2f*vv;
            const size_t idx = base + (size_t)(y0+yy)*64 + x;
            if (FINAL) vv += shortcut[idx];
            out[idx] = vv;
        }
    }
}

extern "C" void kernel_launch(void* const* d_in, const int* in_sizes, int n_in,
                              void* d_out, int out_size, void* d_ws, size_t ws_size,
                              hipStream_t stream)
{
    const float* buffer = (const float*)d_in[0];
    const float* W_in   = (const float*)d_in[1];
    const float* ln1_g  = (const float*)d_in[2];
    const float* ln1_b  = (const float*)d_in[3];
    const float* W_qk   = (const float*)d_in[4];
    const float* W_v    = (const float*)d_in[5];
    const float* W_out  = (const float*)d_in[6];
    const float* ln2_g  = (const float*)d_in[7];
    const float* ln2_b  = (const float*)d_in[8];
    const float* W_ff1  = (const float*)d_in[9];
    const float* W_ff2  = (const float*)d_in[10];
    const float* W_lin  = (const float*)d_in[11];
    const float* cw1    = (const float*)d_in[12];
    const float* cw2    = (const float*)d_in[13];
    const float* cw3    = (const float*)d_in[14];
    float* out = (float*)d_out;
    float* ws0 = (float*)d_ws;           // needs 169,869,312 bytes

    const dim3 tgrid(20736), blk256(256);
    const dim3 cgrid(8*81*8);

    // ---- pass 1 ----
    trans_kernel<1><<<tgrid, blk256, 0, stream>>>(buffer, ws0, W_in, ln1_g, ln1_b,
        W_qk, W_v, W_out, ln2_g, ln2_b, W_ff1, W_ff2, W_lin);
    conv_kernel<false,false><<<cgrid, blk256, 0, stream>>>(ws0, out, cw1, nullptr);
    conv_kernel<false,false><<<cgrid, blk256, 0, stream>>>(out, ws0, cw2, nullptr);
    conv_kernel<false,true ><<<cgrid, blk256, 0, stream>>>(ws0, out, cw3, buffer);  // out = x1

    // ---- pass 2 (tensors kept in (h,w) order; conv taps transposed) ----
    trans_kernel<2><<<tgrid, blk256, 0, stream>>>(out, ws0, W_in, ln1_g, ln1_b,
        W_qk, W_v, W_out, ln2_g, ln2_b, W_ff1, W_ff2, W_lin);
    conv_kernel<true,false><<<cgrid, blk256, 0, stream>>>(ws0, out, cw1, nullptr);
    conv_kernel<true,false><<<cgrid, blk256, 0, stream>>>(out, ws0, cw2, nullptr);
    conv_kernel<true,true ><<<cgrid, blk256, 0, stream>>>(ws0, out, cw3, buffer);   // final
}

// Round 2
// 3536.945 us; speedup vs baseline: 2.9484x; 2.9484x over previous
//
#include <hip/hip_runtime.h>
#include <cmath>

typedef float  f32x4_t  __attribute__((ext_vector_type(4)));
typedef short  bf16x8_t __attribute__((ext_vector_type(8)));

__device__ __forceinline__ unsigned short f2b(float f) {
    unsigned int u = __builtin_bit_cast(unsigned int, f);
    u += 0x7fffu + ((u >> 16) & 1u);          // RNE
    return (unsigned short)(u >> 16);
}
__device__ __forceinline__ float b2f(unsigned short h) {
    return __builtin_bit_cast(float, (unsigned int)h << 16);
}
__device__ __forceinline__ f32x4_t mfma16(bf16x8_t a, bf16x8_t b, f32x4_t c) {
    return __builtin_amdgcn_mfma_f32_16x16x32_bf16(a, b, c, 0, 0, 0);
}

// ---------------- packed-weight layout (bf16 elements) ----------------
// frag layout: pk[off + ((ct*KB + kb)*64 + lane)*8 + i] = W[kb*32+(lane>>4)*8+i][ct*16+(lane&15)]
#define PK_WIN   0        // 64x128,  KB=2
#define PK_WQK   8192     // 128x256, KB=4
#define PK_WV    40960    // 128x128, KB=4
#define PK_WOUT  57344    // 128x128, KB=4
#define PK_WFF1  73728    // 128x256, KB=4
#define PK_WFF2  106496   // 256x128, KB=8
#define PK_WLIN  139264   // 128x64,  KB=4
#define PK_TOTAL 147456

__global__ __launch_bounds__(256)
void pack_kernel(const float* __restrict__ W_in, const float* __restrict__ W_qk,
                 const float* __restrict__ W_v,  const float* __restrict__ W_out,
                 const float* __restrict__ W_ff1,const float* __restrict__ W_ff2,
                 const float* __restrict__ W_lin, unsigned short* __restrict__ pk)
{
    int i = blockIdx.x * 256 + threadIdx.x;
    if (i >= PK_TOTAL) return;
    const float* src; int K, N, off;
    if      (i < PK_WQK)  { src = W_in;  K = 64;  N = 128; off = PK_WIN;  }
    else if (i < PK_WV)   { src = W_qk;  K = 128; N = 256; off = PK_WQK;  }
    else if (i < PK_WOUT) { src = W_v;   K = 128; N = 128; off = PK_WV;   }
    else if (i < PK_WFF1) { src = W_out; K = 128; N = 128; off = PK_WOUT; }
    else if (i < PK_WFF2) { src = W_ff1; K = 128; N = 256; off = PK_WFF1; }
    else if (i < PK_WLIN) { src = W_ff2; K = 256; N = 128; off = PK_WFF2; }
    else                  { src = W_lin; K = 128; N = 64;  off = PK_WLIN; }
    int p = i - off;
    int ei = p & 7, lane = (p >> 3) & 63, rest = p >> 9;
    int KB = K >> 5;
    int kb = rest % KB, ct = rest / KB;
    int k = kb * 32 + ((lane >> 4) << 3) + ei;
    int n = ct * 16 + (lane & 15);
    pk[i] = f2b(src[k * N + n]);
}

// ---------------- LDS pool offsets (bytes) ----------------
// T   fp32 [32][132]  16896   @ 0
// Tn  bf16 [32][136]   8704   @ 16896
// R1 = xs[32][72] / S f32[32][36] / Ob[32][136] / FF[32][264]  16896 @ 25600
// R2 = Q[32][136] / Vt[128][40]   10240 @ 42496
// R3 = K[32][136] / P[32][40]      8704 @ 52736
#define OFF_T  0
#define OFF_TN 16896
#define OFF_R1 25600
#define OFF_R2 42496
#define OFF_R3 52736
#define LDS_SZ 61440

// One block = one n. 4 waves. All GEMMs via 16x16x32 bf16 MFMA.
// PASS 1: h = 2t+ph, w = 2q+pw.   PASS 2: h = 2q+ph, w = 2t+pw.
template<int PASS>
__global__ __launch_bounds__(256)
void trans_mfma(const float* __restrict__ src, unsigned short* __restrict__ dst,
                const unsigned short* __restrict__ pk,
                const float* __restrict__ g1, const float* __restrict__ b1,
                const float* __restrict__ g2, const float* __restrict__ b2)
{
    __shared__ __align__(16) char POOL[LDS_SZ];
    float*          T  = (float*)         (POOL + OFF_T);
    unsigned short* Tn = (unsigned short*)(POOL + OFF_TN);
    unsigned short* xs = (unsigned short*)(POOL + OFF_R1);
    float*          S  = (float*)         (POOL + OFF_R1);
    unsigned short* Ob = (unsigned short*)(POOL + OFF_R1);
    unsigned short* FF = (unsigned short*)(POOL + OFF_R1);
    unsigned short* Q  = (unsigned short*)(POOL + OFF_R2);
    unsigned short* Vt = (unsigned short*)(POOL + OFF_R2);
    unsigned short* Km = (unsigned short*)(POOL + OFF_R3);
    unsigned short* Pp = (unsigned short*)(POOL + OFF_R3);

    const int tid  = threadIdx.x;
    const int lane = tid & 63;
    const int wv   = tid >> 6;
    const int lr   = lane & 15;      // col within tile (C/D), row within tile (A)
    const int lg   = lane >> 4;      // k-group / row-quad selector

    const int n = blockIdx.x;
    const int q = n & 31;
    int r_ = n >> 5;
    const int v_ = r_ % 9; r_ /= 9;
    const int u_ = r_ % 9;
    const int b_ = r_ / 9;
    const size_t plane = (size_t)(b_ * 16) * 81 + (u_ * 9 + v_);

    auto loadAb = [&](const unsigned short* buf, int stride, int rt, int kb) -> bf16x8_t {
        return *(const bf16x8_t*)(buf + (rt * 16 + lr) * stride + kb * 32 + lg * 8);
    };
    auto loadAf = [&](const float* buf, int stride, int rt, int kb) -> bf16x8_t {
        const float* p = buf + (rt * 16 + lr) * stride + kb * 32 + lg * 8;
        f32x4_t lo = *(const f32x4_t*)p, hi = *(const f32x4_t*)(p + 4);
        bf16x8_t r;
        r[0] = (short)f2b(lo[0]); r[1] = (short)f2b(lo[1]);
        r[2] = (short)f2b(lo[2]); r[3] = (short)f2b(lo[3]);
        r[4] = (short)f2b(hi[0]); r[5] = (short)f2b(hi[1]);
        r[6] = (short)f2b(hi[2]); r[7] = (short)f2b(hi[3]);
        return r;
    };
    auto loadBp = [&](int base, int KB, int ct, int kb) -> bf16x8_t {
        return *(const bf16x8_t*)(pk + base + (((ct * KB + kb) * 64 + lane) << 3));
    };

    const float scale = 0.088388347648318447f;   // 1/sqrt(128)

    // ---- gather tokens -> xs bf16 [32][72] ----
    for (int i = tid; i < 32 * 64; i += 256) {
        const int t = i >> 6, cin = i & 63;
        const int c = cin >> 2, ph = (cin >> 1) & 1, pw = cin & 1;
        int hh, ww;
        if (PASS == 1) { hh = 2 * t + ph; ww = 2 * q + pw; }
        else           { hh = 2 * q + ph; ww = 2 * t + pw; }
        xs[t * 72 + cin] = f2b(src[(plane + (size_t)c * 81) * 4096 + hh * 64 + ww]);
    }
    __syncthreads();

    // ---- GEMM1: T = xs @ W_in  (32x64x128) ----
    for (int tt = wv; tt < 16; tt += 4) {
        const int rt = tt & 1, ct = tt >> 1;
        f32x4_t acc = {0.f, 0.f, 0.f, 0.f};
        for (int kb = 0; kb < 2; ++kb)
            acc = mfma16(loadAb(xs, 72, rt, kb), loadBp(PK_WIN, 2, ct, kb), acc);
        const int c = ct * 16 + lr, r0 = rt * 16 + lg * 4;
        for (int i = 0; i < 4; ++i) T[(r0 + i) * 132 + c] = acc[i];
    }
    __syncthreads();

    // ---- LN1: Tn = ln(T)*g1+b1 ----
    {
        const int row = tid >> 3, sub = tid & 7;
        float vals[16]; float sum = 0.f;
        for (int i = 0; i < 16; ++i) { vals[i] = T[row * 132 + sub * 16 + i]; sum += vals[i]; }
        for (int m = 1; m < 8; m <<= 1) sum += __shfl_xor(sum, m, 8);
        const float mean = sum * (1.f / 128.f);
        float var = 0.f;
        for (int i = 0; i < 16; ++i) { float d = vals[i] - mean; var += d * d; }
        for (int m = 1; m < 8; m <<= 1) var += __shfl_xor(var, m, 8);
        const float rstd = rsqrtf(var * (1.f / 128.f) + 1e-5f);
        for (int i = 0; i < 16; ++i) {
            const int col = sub * 16 + i;
            Tn[row * 136 + col] = f2b((vals[i] - mean) * rstd * g1[col] + b1[col]);
        }
    }
    __syncthreads();

    // ---- GEMM2: [Q|K] = (Tn @ W_qk)*scale  (32x128x256) ----
    for (int tt = wv; tt < 32; tt += 4) {
        const int rt = tt & 1, ct = tt >> 1;
        f32x4_t acc = {0.f, 0.f, 0.f, 0.f};
        for (int kb = 0; kb < 4; ++kb)
            acc = mfma16(loadAb(Tn, 136, rt, kb), loadBp(PK_WQK, 4, ct, kb), acc);
        const int c = ct * 16 + lr, r0 = rt * 16 + lg * 4;
        if (c < 128) for (int i = 0; i < 4; ++i) Q [(r0 + i) * 136 + c      ] = f2b(acc[i] * scale);
        else         for (int i = 0; i < 4; ++i) Km[(r0 + i) * 136 + c - 128] = f2b(acc[i] * scale);
    }
    __syncthreads();

    // ---- scores: S = Q @ K^T  (32x128x32) — B-frag = row reads of Km ----
    {
        const int rt = wv & 1, ct = wv >> 1;
        f32x4_t acc = {0.f, 0.f, 0.f, 0.f};
        for (int kb = 0; kb < 4; ++kb)
            acc = mfma16(loadAb(Q, 136, rt, kb), loadAb(Km, 136, ct, kb), acc);
        const int c = ct * 16 + lr, r0 = rt * 16 + lg * 4;
        for (int i = 0; i < 4; ++i) S[(r0 + i) * 36 + c] = acc[i];
    }
    __syncthreads();

    // ---- softmax rows of S -> P bf16 [32][40]; plus Wv: Vt = (T @ W_v)^T * scale ----
    {
        const int row = tid >> 3, sub = tid & 7;
        float v4[4]; float mx = -1e30f;
        for (int i = 0; i < 4; ++i) { v4[i] = S[row * 36 + sub * 4 + i]; mx = fmaxf(mx, v4[i]); }
        for (int m = 1; m < 8; m <<= 1) mx = fmaxf(mx, __shfl_xor(mx, m, 8));
        float sm = 0.f;
        for (int i = 0; i < 4; ++i) { v4[i] = expf(v4[i] - mx); sm += v4[i]; }
        for (int m = 1; m < 8; m <<= 1) sm += __shfl_xor(sm, m, 8);
        const float inv = 1.f / sm;
        for (int i = 0; i < 4; ++i) Pp[row * 40 + sub * 4 + i] = f2b(v4[i] * inv);
    }
    for (int tt = wv; tt < 16; tt += 4) {      // Wv (reads T, writes Vt — both safe here)
        const int rt = tt & 1, ct = tt >> 1;
        f32x4_t acc = {0.f, 0.f, 0.f, 0.f};
        for (int kb = 0; kb < 4; ++kb)
            acc = mfma16(loadAf(T, 132, rt, kb), loadBp(PK_WV, 4, ct, kb), acc);
        const int c = ct * 16 + lr, r0 = rt * 16 + lg * 4;
        short4 s4;
        s4.x = (short)f2b(acc[0] * scale); s4.y = (short)f2b(acc[1] * scale);
        s4.z = (short)f2b(acc[2] * scale); s4.w = (short)f2b(acc[3] * scale);
        *(short4*)(Vt + c * 40 + r0) = s4;     // transposed store, 8B
    }
    __syncthreads();

    // ---- PV: Ob = P @ V  (32x32x128) — B-frag = row reads of Vt ----
    for (int tt = wv; tt < 16; tt += 4) {
        const int rt = tt & 1, ct = tt >> 1;
        f32x4_t acc = {0.f, 0.f, 0.f, 0.f};
        acc = mfma16(loadAb(Pp, 40, rt, 0), loadAb(Vt, 40, ct, 0), acc);
        const int c = ct * 16 + lr, r0 = rt * 16 + lg * 4;
        for (int i = 0; i < 4; ++i) Ob[(r0 + i) * 136 + c] = f2b(acc[i]);
    }
    __syncthreads();

    // ---- Wout: T += Ob @ W_out ----
    for (int tt = wv; tt < 16; tt += 4) {
        const int rt = tt & 1, ct = tt >> 1;
        f32x4_t acc = {0.f, 0.f, 0.f, 0.f};
        for (int kb = 0; kb < 4; ++kb)
            acc = mfma16(loadAb(Ob, 136, rt, kb), loadBp(PK_WOUT, 4, ct, kb), acc);
        const int c = ct * 16 + lr, r0 = rt * 16 + lg * 4;
        for (int i = 0; i < 4; ++i) T[(r0 + i) * 132 + c] += acc[i];
    }
    __syncthreads();

    // ---- LN2 -> Tn ----
    {
        const int row = tid >> 3, sub = tid & 7;
        float vals[16]; float sum = 0.f;
        for (int i = 0; i < 16; ++i) { vals[i] = T[row * 132 + sub * 16 + i]; sum += vals[i]; }
        for (int m = 1; m < 8; m <<= 1) sum += __shfl_xor(sum, m, 8);
        const float mean = sum * (1.f / 128.f);
        float var = 0.f;
        for (int i = 0; i < 16; ++i) { float d = vals[i] - mean; var += d * d; }
        for (int m = 1; m < 8; m <<= 1) var += __shfl_xor(var, m, 8);
        const float rstd = rsqrtf(var * (1.f / 128.f) + 1e-5f);
        for (int i = 0; i < 16; ++i) {
            const int col = sub * 16 + i;
            Tn[row * 136 + col] = f2b((vals[i] - mean) * rstd * g2[col] + b2[col]);
        }
    }
    __syncthreads();

    // ---- ff1: FF = gelu(Tn @ W_ff1)  (32x128x256) ----
    for (int tt = wv; tt < 32; tt += 4) {
        const int rt = tt & 1, ct = tt >> 1;
        f32x4_t acc = {0.f, 0.f, 0.f, 0.f};
        for (int kb = 0; kb < 4; ++kb)
            acc = mfma16(loadAb(Tn, 136, rt, kb), loadBp(PK_WFF1, 4, ct, kb), acc);
        const int c = ct * 16 + lr, r0 = rt * 16 + lg * 4;
        for (int i = 0; i < 4; ++i) {
            const float x = acc[i];
            FF[(r0 + i) * 264 + c] = f2b(0.5f * x * (1.f + erff(x * 0.70710678118654752f)));
        }
    }
    __syncthreads();

    // ---- ff2: T += FF @ W_ff2  (32x256x128) ----
    for (int tt = wv; tt < 16; tt += 4) {
        const int rt = tt & 1, ct = tt >> 1;
        f32x4_t acc = {0.f, 0.f, 0.f, 0.f};
        for (int kb = 0; kb < 8; ++kb)
            acc = mfma16(loadAb(FF, 264, rt, kb), loadBp(PK_WFF2, 8, ct, kb), acc);
        const int c = ct * 16 + lr, r0 = rt * 16 + lg * 4;
        for (int i = 0; i < 4; ++i) T[(r0 + i) * 132 + c] += acc[i];
    }
    __syncthreads();

    // ---- Wlin: Y = T @ W_lin (32x128x64) -> scatter bf16 to dst ----
    for (int tt = wv; tt < 8; tt += 4) {
        const int rt = tt & 1, ct = tt >> 1;
        f32x4_t acc = {0.f, 0.f, 0.f, 0.f};
        for (int kb = 0; kb < 4; ++kb)
            acc = mfma16(loadAf(T, 132, rt, kb), loadBp(PK_WLIN, 4, ct, kb), acc);
        const int cin = ct * 16 + lr, r0 = rt * 16 + lg * 4;
        const int c = cin >> 2, ph = (cin >> 1) & 1, pw = cin & 1;
        for (int i = 0; i < 4; ++i) {
            const int t = r0 + i;
            int hh, ww;
            if (PASS == 1) { hh = 2 * t + ph; ww = 2 * q + pw; }
            else           { hh = 2 * q + ph; ww = 2 * t + pw; }
            dst[(plane + (size_t)c * 81) * 4096 + hh * 64 + ww] = f2b(acc[i]);
        }
    }
}

// 3x3 conv 16->16 ch, pad 1, leaky 0.2. SRCB/DSTB: bf16 in/out. SWAPW: transpose taps.
template<bool SRCB, bool DSTB, bool SWAPW, bool FINAL>
__global__ __launch_bounds__(256)
void conv_kernel(const void* __restrict__ in_, void* __restrict__ out_,
                 const float* __restrict__ wgt, const float* __restrict__ shortcut)
{
    __shared__ float tin[16][10][64];
    __shared__ float wl[16][16][9];

    const float*          inf = (const float*)in_;
    const unsigned short* inb = (const unsigned short*)in_;
    float*          outf = (float*)out_;
    unsigned short* outb = (unsigned short*)out_;

    const int tid = threadIdx.x;
    const int blk = blockIdx.x;
    const int yt = blk & 7;
    const int bs = blk >> 3;
    const int s_ = bs % 81;
    const int b_ = bs / 81;
    const int y0 = yt * 8;

    for (int i = tid; i < 16 * 10 * 64; i += 256) {
        const int ci = i / 640, rem = i % 640;
        const int yy = rem >> 6, x = rem & 63;
        const int y = y0 + yy - 1;
        float vv = 0.f;
        if (y >= 0 && y < 64) {
            const size_t idx = ((size_t)(b_ * 16 + ci) * 81 + s_) * 4096 + y * 64 + x;
            vv = SRCB ? b2f(inb[idx]) : inf[idx];
        }
        tin[ci][yy][x] = vv;
    }
    for (int i = tid; i < 16 * 16 * 9; i += 256) {
        const int co = i / 144, rem = i % 144;
        const int ci = rem / 9, k = rem % 9;
        const int dy = k / 3, dx = k % 3;
        wl[co][ci][SWAPW ? (dx * 3 + dy) : k] = wgt[i];
    }
    __syncthreads();

    const int x = tid & 63;
    const int cog = tid >> 6;

    float acc[4][8] = {};
    for (int ci = 0; ci < 16; ++ci) {
        float inr[10][3];
        for (int yy = 0; yy < 10; ++yy) {
            inr[yy][0] = (x > 0)  ? tin[ci][yy][x - 1] : 0.f;
            inr[yy][1] = tin[ci][yy][x];
            inr[yy][2] = (x < 63) ? tin[ci][yy][x + 1] : 0.f;
        }
        float wr[4][9];
        for (int j = 0; j < 4; ++j)
            for (int k = 0; k < 9; ++k) wr[j][k] = wl[cog * 4 + j][ci][k];
        for (int j = 0; j < 4; ++j)
            for (int dy = 0; dy < 3; ++dy)
                for (int dx = 0; dx < 3; ++dx) {
                    const float w = wr[j][dy * 3 + dx];
                    for (int yy = 0; yy < 8; ++yy)
                        acc[j][yy] += inr[yy + dy][dx] * w;
                }
    }

    for (int j = 0; j < 4; ++j) {
        const int co = cog * 4 + j;
        const size_t base = ((size_t)(b_ * 16 + co) * 81 + s_) * 4096;
        for (int yy = 0; yy < 8; ++yy) {
            float vv = acc[j][yy];
            vv = (vv >= 0.f) ? vv : 0.2f * vv;
            const size_t idx = base + (size_t)(y0 + yy) * 64 + x;
            if (FINAL) vv += shortcut[idx];
            if (DSTB) outb[idx] = f2b(vv); else outf[idx] = vv;
        }
    }
}

extern "C" void kernel_launch(void* const* d_in, const int* in_sizes, int n_in,
                              void* d_out, int out_size, void* d_ws, size_t ws_size,
                              hipStream_t stream)
{
    const float* buffer = (const float*)d_in[0];
    const float* W_in   = (const float*)d_in[1];
    const float* ln1_g  = (const float*)d_in[2];
    const float* ln1_b  = (const float*)d_in[3];
    const float* W_qk   = (const float*)d_in[4];
    const float* W_v    = (const float*)d_in[5];
    const float* W_out  = (const float*)d_in[6];
    const float* ln2_g  = (const float*)d_in[7];
    const float* ln2_b  = (const float*)d_in[8];
    const float* W_ff1  = (const float*)d_in[9];
    const float* W_ff2  = (const float*)d_in[10];
    const float* W_lin  = (const float*)d_in[11];
    const float* cw1    = (const float*)d_in[12];
    const float* cw2    = (const float*)d_in[13];
    const float* cw3    = (const float*)d_in[14];
    float* out = (float*)d_out;

    // ws layout: [0, 84934656) bf16 activation tensor; packed weights after it.
    unsigned short* wsb = (unsigned short*)d_ws;
    unsigned short* pkw = (unsigned short*)((char*)d_ws + 84934656);

    const dim3 blk256(256);
    const dim3 tgrid(20736);
    const dim3 cgrid(8 * 81 * 8);

    pack_kernel<<<dim3(576), blk256, 0, stream>>>(W_in, W_qk, W_v, W_out, W_ff1, W_ff2, W_lin, pkw);

    // ---- pass 1 ----
    trans_mfma<1><<<tgrid, blk256, 0, stream>>>(buffer, wsb, pkw, ln1_g, ln1_b, ln2_g, ln2_b);
    conv_kernel<true,  false, false, false><<<cgrid, blk256, 0, stream>>>(wsb, out, cw1, nullptr);
    conv_kernel<false, true,  false, false><<<cgrid, blk256, 0, stream>>>(out, wsb, cw2, nullptr);
    conv_kernel<true,  false, false, true ><<<cgrid, blk256, 0, stream>>>(wsb, out, cw3, buffer);  // x1 (fp32)

    // ---- pass 2 (tensors in (h,w) order; conv taps transposed) ----
    trans_mfma<2><<<tgrid, blk256, 0, stream>>>(out, wsb, pkw, ln1_g, ln1_b, ln2_g, ln2_b);
    conv_kernel<true,  false, true,  false><<<cgrid, blk256, 0, stream>>>(wsb, out, cw1, nullptr);
    conv_kernel<false, true,  true,  false><<<cgrid, blk256, 0, stream>>>(out, wsb, cw2, nullptr);
    conv_kernel<true,  false, true,  true ><<<cgrid, blk256, 0, stream>>>(wsb, out, cw3, buffer);  // final
}

// Round 3
// 2168.323 us; speedup vs baseline: 4.8093x; 1.6312x over previous
//
#include <hip/hip_runtime.h>
#include <cmath>

typedef float  f32x4_t  __attribute__((ext_vector_type(4)));
typedef short  bf16x8_t __attribute__((ext_vector_type(8)));

__device__ __forceinline__ unsigned short f2b(float f) {
    unsigned int u = __builtin_bit_cast(unsigned int, f);
    u += 0x7fffu + ((u >> 16) & 1u);          // RNE
    return (unsigned short)(u >> 16);
}
__device__ __forceinline__ float b2f(unsigned short h) {
    return __builtin_bit_cast(float, (unsigned int)h << 16);
}
__device__ __forceinline__ f32x4_t mfma16(bf16x8_t a, bf16x8_t b, f32x4_t c) {
    return __builtin_amdgcn_mfma_f32_16x16x32_bf16(a, b, c, 0, 0, 0);
}

// ---------------- packed-weight layout (bf16 elements) ----------------
// pk[off + ((ct*KB + kb)*64 + lane)*8 + i] = W[kb*32+(lane>>4)*8+i][ct*16+(lane&15)]
#define PK_WIN   0        // 64x128,  KB=2
#define PK_WQK   8192     // 128x256, KB=4
#define PK_WV    40960    // 128x128, KB=4
#define PK_WOUT  57344    // 128x128, KB=4
#define PK_WFF1  73728    // 128x256, KB=4
#define PK_WFF2  106496   // 256x128, KB=8
#define PK_WLIN  139264   // 128x64,  KB=4
#define PK_TOTAL 147456

__global__ __launch_bounds__(256)
void pack_kernel(const float* __restrict__ W_in, const float* __restrict__ W_qk,
                 const float* __restrict__ W_v,  const float* __restrict__ W_out,
                 const float* __restrict__ W_ff1,const float* __restrict__ W_ff2,
                 const float* __restrict__ W_lin, unsigned short* __restrict__ pk)
{
    int i = blockIdx.x * 256 + threadIdx.x;
    if (i >= PK_TOTAL) return;
    const float* src; int K, N, off;
    if      (i < PK_WQK)  { src = W_in;  K = 64;  N = 128; off = PK_WIN;  }
    else if (i < PK_WV)   { src = W_qk;  K = 128; N = 256; off = PK_WQK;  }
    else if (i < PK_WOUT) { src = W_v;   K = 128; N = 128; off = PK_WV;   }
    else if (i < PK_WFF1) { src = W_out; K = 128; N = 128; off = PK_WOUT; }
    else if (i < PK_WFF2) { src = W_ff1; K = 128; N = 256; off = PK_WFF1; }
    else if (i < PK_WLIN) { src = W_ff2; K = 256; N = 128; off = PK_WFF2; }
    else                  { src = W_lin; K = 128; N = 64;  off = PK_WLIN; }
    int p = i - off;
    int ei = p & 7, lane = (p >> 3) & 63, rest = p >> 9;
    int KB = K >> 5;
    int kb = rest % KB, ct = rest / KB;
    int k = kb * 32 + ((lane >> 4) << 3) + ei;
    int n = ct * 16 + (lane & 15);
    pk[i] = f2b(src[k * N + n]);
}

// ---------------- LDS pool (44544 B -> 3 blocks/CU) ----------------
// T  f32 [32][132] 16896 @ 0        (residual, live whole kernel)
// S1  8704 @ 16896 : xs[32][72] | Tn[32][136] | S f32[32][36] | Ob[32][136]
// S2 10240 @ 25600 : Q[32][136] | Vt[128][40] | FF[32][264] (spans S2+S3)
// S3  8704 @ 35840 : Km[32][136] | Pp[32][40]
#define OFF_S1 16896
#define OFF_S2 25600
#define OFF_S3 35840
#define LDS_SZ 44544

// One block = one n, 4 waves, 16x16x32 bf16 MFMA everywhere.
// PASS 1: h = 2t+ph, w = 2q+pw.   PASS 2: h = 2q+ph, w = 2t+pw.
template<int PASS, bool SRCB>
__global__ __launch_bounds__(256, 3)
void trans_mfma(const void* __restrict__ src_, unsigned short* __restrict__ dst,
                const unsigned short* __restrict__ pk,
                const float* __restrict__ g1, const float* __restrict__ b1,
                const float* __restrict__ g2, const float* __restrict__ b2)
{
    __shared__ __align__(16) char POOL[LDS_SZ];
    float*          T   = (float*)POOL;                       // [32][132]
    unsigned short* xs  = (unsigned short*)(POOL + OFF_S1);   // [32][72]
    unsigned short* Tn  = (unsigned short*)(POOL + OFF_S1);   // [32][136]
    float*          Ssc = (float*)         (POOL + OFF_S1);   // [32][36]
    unsigned short* Ob  = (unsigned short*)(POOL + OFF_S1);   // [32][136]
    unsigned short* Q   = (unsigned short*)(POOL + OFF_S2);   // [32][136]
    unsigned short* Vt  = (unsigned short*)(POOL + OFF_S2);   // [128][40]
    unsigned short* FF  = (unsigned short*)(POOL + OFF_S2);   // [32][264]
    unsigned short* Km  = (unsigned short*)(POOL + OFF_S3);   // [32][136]
    unsigned short* Pp  = (unsigned short*)(POOL + OFF_S3);   // [32][40]

    const int tid  = threadIdx.x;
    const int lane = tid & 63;
    const int wv   = tid >> 6;
    const int lr   = lane & 15;
    const int lg   = lane >> 4;

    // XCD-bijective swizzle: plane's 32 q-blocks land on one XCD (L2 line merge)
    const int bid = blockIdx.x;
    const int n = (bid & 7) * 2592 + (bid >> 3);
    const int q = n & 31;
    int r_ = n >> 5;
    const int v_ = r_ % 9; r_ /= 9;
    const int u_ = r_ % 9;
    const int b_ = r_ / 9;
    const size_t plane = (size_t)(b_ * 16) * 81 + (u_ * 9 + v_);

    auto ldA = [&](const unsigned short* buf, int stride, int rt, int kb) -> bf16x8_t {
        return *(const bf16x8_t*)(buf + (rt * 16 + lr) * stride + kb * 32 + lg * 8);
    };
    auto ldAf = [&](const float* buf, int stride, int rt, int kb) -> bf16x8_t {
        const float* p = buf + (rt * 16 + lr) * stride + kb * 32 + lg * 8;
        f32x4_t lo = *(const f32x4_t*)p, hi = *(const f32x4_t*)(p + 4);
        bf16x8_t r;
        r[0] = (short)f2b(lo[0]); r[1] = (short)f2b(lo[1]);
        r[2] = (short)f2b(lo[2]); r[3] = (short)f2b(lo[3]);
        r[4] = (short)f2b(hi[0]); r[5] = (short)f2b(hi[1]);
        r[6] = (short)f2b(hi[2]); r[7] = (short)f2b(hi[3]);
        return r;
    };
    auto ldB = [&](int base, int KB, int ct, int kb) -> bf16x8_t {
        return *(const bf16x8_t*)(pk + base + (((ct * KB + kb) * 64 + lane) << 3));
    };

    const float scale = 0.088388347648318447f;   // 1/sqrt(128)

    // ---- gather tokens -> xs bf16 [32][72] ----
    {
        const float* srcf = (const float*)src_;
        const unsigned short* srcb = (const unsigned short*)src_;
        for (int i = tid; i < 32 * 64; i += 256) {
            const int t = i >> 6, cin = i & 63;
            const int c = cin >> 2, ph = (cin >> 1) & 1, pw = cin & 1;
            int hh, ww;
            if (PASS == 1) { hh = 2 * t + ph; ww = 2 * q + pw; }
            else           { hh = 2 * q + ph; ww = 2 * t + pw; }
            const size_t idx = (plane + (size_t)c * 81) * 4096 + hh * 64 + ww;
            xs[t * 72 + cin] = SRCB ? srcb[idx] : f2b(srcf[idx]);
        }
    }
    __syncthreads();

    // ---- G1: T = xs @ W_in (32x64x128). wave: ct {2w,2w+1} x rt {0,1} ----
    {
        const int ct0 = 2 * wv;
        bf16x8_t a[2][2], b[2][2];
        #pragma unroll
        for (int r = 0; r < 2; ++r) for (int k = 0; k < 2; ++k) a[r][k] = ldA(xs, 72, r, k);
        #pragma unroll
        for (int c = 0; c < 2; ++c) for (int k = 0; k < 2; ++k) b[c][k] = ldB(PK_WIN, 2, ct0 + c, k);
        #pragma unroll
        for (int r = 0; r < 2; ++r)
        #pragma unroll
        for (int c = 0; c < 2; ++c) {
            f32x4_t acc = {0.f, 0.f, 0.f, 0.f};
            acc = mfma16(a[r][0], b[c][0], acc);
            acc = mfma16(a[r][1], b[c][1], acc);
            const int col = (ct0 + c) * 16 + lr, r0 = r * 16 + lg * 4;
            #pragma unroll
            for (int i = 0; i < 4; ++i) T[(r0 + i) * 132 + col] = acc[i];
        }
    }
    __syncthreads();

    // ---- LN1 -> Tn ----
    {
        const int row = tid >> 3, sub = tid & 7;
        float vals[16]; float sum = 0.f;
        #pragma unroll
        for (int i = 0; i < 16; ++i) { vals[i] = T[row * 132 + sub * 16 + i]; sum += vals[i]; }
        #pragma unroll
        for (int m = 1; m < 8; m <<= 1) sum += __shfl_xor(sum, m, 8);
        const float mean = sum * (1.f / 128.f);
        float var = 0.f;
        #pragma unroll
        for (int i = 0; i < 16; ++i) { float d = vals[i] - mean; var += d * d; }
        #pragma unroll
        for (int m = 1; m < 8; m <<= 1) var += __shfl_xor(var, m, 8);
        const float rstd = rsqrtf(var * (1.f / 128.f) + 1e-5f);
        #pragma unroll
        for (int i = 0; i < 16; ++i) {
            const int col = sub * 16 + i;
            Tn[row * 136 + col] = f2b((vals[i] - mean) * rstd * g1[col] + b1[col]);
        }
    }
    __syncthreads();

    // ---- G2: [Q|K] = (Tn @ W_qk)*scale (32x128x256), two 128-col halves ----
    {
        bf16x8_t a[2][4];
        #pragma unroll
        for (int r = 0; r < 2; ++r) for (int k = 0; k < 4; ++k) a[r][k] = ldA(Tn, 136, r, k);
        #pragma unroll
        for (int h = 0; h < 2; ++h) {
            const int ct0 = h * 8 + 2 * wv;
            bf16x8_t b[2][4];
            #pragma unroll
            for (int c = 0; c < 2; ++c) for (int k = 0; k < 4; ++k) b[c][k] = ldB(PK_WQK, 4, ct0 + c, k);
            unsigned short* dsth = h ? Km : Q;
            #pragma unroll
            for (int r = 0; r < 2; ++r)
            #pragma unroll
            for (int c = 0; c < 2; ++c) {
                f32x4_t acc = {0.f, 0.f, 0.f, 0.f};
                #pragma unroll
                for (int k = 0; k < 4; ++k) acc = mfma16(a[r][k], b[c][k], acc);
                const int col = (ct0 + c - h * 8) * 16 + lr, r0 = r * 16 + lg * 4;
                #pragma unroll
                for (int i = 0; i < 4; ++i) dsth[(r0 + i) * 136 + col] = f2b(acc[i] * scale);
            }
        }
    }
    __syncthreads();

    // ---- scores: S = Q @ K^T (32x128x32), 1 tile/wave ----
    {
        const int rt = wv & 1, ct = wv >> 1;
        bf16x8_t a[4], b[4];
        #pragma unroll
        for (int k = 0; k < 4; ++k) { a[k] = ldA(Q, 136, rt, k); b[k] = ldA(Km, 136, ct, k); }
        f32x4_t acc = {0.f, 0.f, 0.f, 0.f};
        #pragma unroll
        for (int k = 0; k < 4; ++k) acc = mfma16(a[k], b[k], acc);
        const int col = ct * 16 + lr, r0 = rt * 16 + lg * 4;
        #pragma unroll
        for (int i = 0; i < 4; ++i) Ssc[(r0 + i) * 36 + col] = acc[i];
    }
    __syncthreads();

    // ---- softmax(S) -> Pp bf16 ; Wv: Vt = (T @ W_v)^T * scale ----
    {
        const int row = tid >> 3, sub = tid & 7;
        float v4[4]; float mx = -1e30f;
        #pragma unroll
        for (int i = 0; i < 4; ++i) { v4[i] = Ssc[row * 36 + sub * 4 + i]; mx = fmaxf(mx, v4[i]); }
        #pragma unroll
        for (int m = 1; m < 8; m <<= 1) mx = fmaxf(mx, __shfl_xor(mx, m, 8));
        float sm = 0.f;
        #pragma unroll
        for (int i = 0; i < 4; ++i) { v4[i] = expf(v4[i] - mx); sm += v4[i]; }
        #pragma unroll
        for (int m = 1; m < 8; m <<= 1) sm += __shfl_xor(sm, m, 8);
        const float inv = 1.f / sm;
        short4 p4;
        p4.x = (short)f2b(v4[0] * inv); p4.y = (short)f2b(v4[1] * inv);
        p4.z = (short)f2b(v4[2] * inv); p4.w = (short)f2b(v4[3] * inv);
        *(short4*)(Pp + row * 40 + sub * 4) = p4;
    }
    {
        const int ct0 = 2 * wv;
        bf16x8_t b[2][4];
        #pragma unroll
        for (int c = 0; c < 2; ++c) for (int k = 0; k < 4; ++k) b[c][k] = ldB(PK_WV, 4, ct0 + c, k);
        #pragma unroll
        for (int r = 0; r < 2; ++r) {
            bf16x8_t a[4];
            #pragma unroll
            for (int k = 0; k < 4; ++k) a[k] = ldAf(T, 132, r, k);
            #pragma unroll
            for (int c = 0; c < 2; ++c) {
                f32x4_t acc = {0.f, 0.f, 0.f, 0.f};
                #pragma unroll
                for (int k = 0; k < 4; ++k) acc = mfma16(a[k], b[c][k], acc);
                const int col = (ct0 + c) * 16 + lr, r0 = r * 16 + lg * 4;
                short4 s4;
                s4.x = (short)f2b(acc[0] * scale); s4.y = (short)f2b(acc[1] * scale);
                s4.z = (short)f2b(acc[2] * scale); s4.w = (short)f2b(acc[3] * scale);
                *(short4*)(Vt + col * 40 + r0) = s4;   // transposed store
            }
        }
    }
    __syncthreads();

    // ---- PV: Ob = P @ V (32x32x128) ----
    {
        const int ct0 = 2 * wv;
        bf16x8_t a0 = ldA(Pp, 40, 0, 0), a1 = ldA(Pp, 40, 1, 0);
        bf16x8_t b0 = ldA(Vt, 40, ct0, 0), b1 = ldA(Vt, 40, ct0 + 1, 0);
        bf16x8_t aa[2] = {a0, a1}, bb[2] = {b0, b1};
        #pragma unroll
        for (int r = 0; r < 2; ++r)
        #pragma unroll
        for (int c = 0; c < 2; ++c) {
            f32x4_t acc = {0.f, 0.f, 0.f, 0.f};
            acc = mfma16(aa[r], bb[c], acc);
            const int col = (ct0 + c) * 16 + lr, r0 = r * 16 + lg * 4;
            #pragma unroll
            for (int i = 0; i < 4; ++i) Ob[(r0 + i) * 136 + col] = f2b(acc[i]);
        }
    }
    __syncthreads();

    // ---- Wout: T += Ob @ W_out ----
    {
        const int ct0 = 2 * wv;
        bf16x8_t a[2][4], b[2][4];
        #pragma unroll
        for (int r = 0; r < 2; ++r) for (int k = 0; k < 4; ++k) a[r][k] = ldA(Ob, 136, r, k);
        #pragma unroll
        for (int c = 0; c < 2; ++c) for (int k = 0; k < 4; ++k) b[c][k] = ldB(PK_WOUT, 4, ct0 + c, k);
        #pragma unroll
        for (int r = 0; r < 2; ++r)
        #pragma unroll
        for (int c = 0; c < 2; ++c) {
            f32x4_t acc = {0.f, 0.f, 0.f, 0.f};
            #pragma unroll
            for (int k = 0; k < 4; ++k) acc = mfma16(a[r][k], b[c][k], acc);
            const int col = (ct0 + c) * 16 + lr, r0 = r * 16 + lg * 4;
            #pragma unroll
            for (int i = 0; i < 4; ++i) T[(r0 + i) * 132 + col] += acc[i];
        }
    }
    __syncthreads();

    // ---- LN2 -> Tn ----
    {
        const int row = tid >> 3, sub = tid & 7;
        float vals[16]; float sum = 0.f;
        #pragma unroll
        for (int i = 0; i < 16; ++i) { vals[i] = T[row * 132 + sub * 16 + i]; sum += vals[i]; }
        #pragma unroll
        for (int m = 1; m < 8; m <<= 1) sum += __shfl_xor(sum, m, 8);
        const float mean = sum * (1.f / 128.f);
        float var = 0.f;
        #pragma unroll
        for (int i = 0; i < 16; ++i) { float d = vals[i] - mean; var += d * d; }
        #pragma unroll
        for (int m = 1; m < 8; m <<= 1) var += __shfl_xor(var, m, 8);
        const float rstd = rsqrtf(var * (1.f / 128.f) + 1e-5f);
        #pragma unroll
        for (int i = 0; i < 16; ++i) {
            const int col = sub * 16 + i;
            Tn[row * 136 + col] = f2b((vals[i] - mean) * rstd * g2[col] + b2[col]);
        }
    }
    __syncthreads();

    // ---- ff1: FF = gelu(Tn @ W_ff1) (32x128x256) ----
    {
        bf16x8_t a[2][4];
        #pragma unroll
        for (int r = 0; r < 2; ++r) for (int k = 0; k < 4; ++k) a[r][k] = ldA(Tn, 136, r, k);
        #pragma unroll
        for (int h = 0; h < 2; ++h) {
            const int ct0 = h * 8 + 2 * wv;
            bf16x8_t b[2][4];
            #pragma unroll
            for (int c = 0; c < 2; ++c) for (int k = 0; k < 4; ++k) b[c][k] = ldB(PK_WFF1, 4, ct0 + c, k);
            #pragma unroll
            for (int r = 0; r < 2; ++r)
            #pragma unroll
            for (int c = 0; c < 2; ++c) {
                f32x4_t acc = {0.f, 0.f, 0.f, 0.f};
                #pragma unroll
                for (int k = 0; k < 4; ++k) acc = mfma16(a[r][k], b[c][k], acc);
                const int col = (ct0 + c) * 16 + lr, r0 = r * 16 + lg * 4;
                #pragma unroll
                for (int i = 0; i < 4; ++i) {
                    const float x = acc[i];
                    FF[(r0 + i) * 264 + col] = f2b(0.5f * x * (1.f + erff(x * 0.70710678118654752f)));
                }
            }
        }
    }
    __syncthreads();

    // ---- ff2: T += FF @ W_ff2 (32x256x128), two K-halves ----
    {
        const int ct0 = 2 * wv;
        f32x4_t acc[2][2] = {};
        #pragma unroll
        for (int half = 0; half < 2; ++half) {
            bf16x8_t a[2][4], b[2][4];
            #pragma unroll
            for (int r = 0; r < 2; ++r) for (int k = 0; k < 4; ++k) a[r][k] = ldA(FF, 264, r, half * 4 + k);
            #pragma unroll
            for (int c = 0; c < 2; ++c) for (int k = 0; k < 4; ++k) b[c][k] = ldB(PK_WFF2, 8, ct0 + c, half * 4 + k);
            #pragma unroll
            for (int r = 0; r < 2; ++r)
            #pragma unroll
            for (int c = 0; c < 2; ++c)
            #pragma unroll
            for (int k = 0; k < 4; ++k) acc[r][c] = mfma16(a[r][k], b[c][k], acc[r][c]);
        }
        #pragma unroll
        for (int r = 0; r < 2; ++r)
        #pragma unroll
        for (int c = 0; c < 2; ++c) {
            const int col = (ct0 + c) * 16 + lr, r0 = r * 16 + lg * 4;
            #pragma unroll
            for (int i = 0; i < 4; ++i) T[(r0 + i) * 132 + col] += acc[r][c][i];
        }
    }
    __syncthreads();

    // ---- Wlin: Y = T @ W_lin (32x128x64) -> scatter bf16 ----
    {
        const int ct = wv;
        bf16x8_t b[4];
        #pragma unroll
        for (int k = 0; k < 4; ++k) b[k] = ldB(PK_WLIN, 4, ct, k);
        #pragma unroll
        for (int r = 0; r < 2; ++r) {
            bf16x8_t a[4];
            #pragma unroll
            for (int k = 0; k < 4; ++k) a[k] = ldAf(T, 132, r, k);
            f32x4_t acc = {0.f, 0.f, 0.f, 0.f};
            #pragma unroll
            for (int k = 0; k < 4; ++k) acc = mfma16(a[k], b[k], acc);
            const int cin = ct * 16 + lr, r0 = r * 16 + lg * 4;
            const int c = cin >> 2, ph = (cin >> 1) & 1, pw = cin & 1;
            #pragma unroll
            for (int i = 0; i < 4; ++i) {
                const int t = r0 + i;
                int hh, ww;
                if (PASS == 1) { hh = 2 * t + ph; ww = 2 * q + pw; }
                else           { hh = 2 * q + ph; ww = 2 * t + pw; }
                dst[(plane + (size_t)c * 81) * 4096 + hh * 64 + ww] = f2b(acc[i]);
            }
        }
    }
}

// 3x3 conv 16->16 ch, pad 1, leaky 0.2. SRCB/DSTB: bf16 in/out. SWAPW: transposed taps.
template<bool SRCB, bool DSTB, bool SWAPW, bool FINAL>
__global__ __launch_bounds__(256, 3)
void conv_kernel(const void* __restrict__ in_, void* __restrict__ out_,
                 const float* __restrict__ wgt, const float* __restrict__ shortcut)
{
    __shared__ float tin[16][10][66];   // padded: col 0 and 65 are zero
    __shared__ float wl[16][16][9];

    const float*          inf = (const float*)in_;
    const unsigned short* inb = (const unsigned short*)in_;
    float*          outf = (float*)out_;
    unsigned short* outb = (unsigned short*)out_;

    const int tid = threadIdx.x;
    const int blk = blockIdx.x;
    const int yt = blk & 7;
    const int bs = blk >> 3;
    const int s_ = bs % 81;
    const int b_ = bs / 81;
    const int y0 = yt * 8;

    // zero the halo columns
    for (int i = tid; i < 320; i += 256) {
        const int ci = i / 20, rem = i % 20, yy = rem >> 1, e = rem & 1;
        tin[ci][yy][e * 65] = 0.f;
    }
    // paired loads (2 elems/thread/iter)
    for (int i = tid; i < 5120; i += 256) {
        const int yy = i >> 9, rem = i & 511, ci = rem >> 5, xp = rem & 31;
        const int y = y0 + yy - 1;
        float v0 = 0.f, v1 = 0.f;
        if (y >= 0 && y < 64) {
            const size_t base = ((size_t)(b_ * 16 + ci) * 81 + s_) * 4096 + y * 64 + xp * 2;
            if (SRCB) {
                unsigned int u = *(const unsigned int*)(inb + base);
                v0 = b2f((unsigned short)(u & 0xffffu)); v1 = b2f((unsigned short)(u >> 16));
            } else {
                float2 f = *(const float2*)(inf + base);
                v0 = f.x; v1 = f.y;
            }
        }
        tin[ci][yy][xp * 2 + 1] = v0;
        tin[ci][yy][xp * 2 + 2] = v1;
    }
    for (int i = tid; i < 16 * 16 * 9; i += 256) {
        const int co = i / 144, rem = i % 144;
        const int ci = rem / 9, k = rem % 9;
        const int dy = k / 3, dx = k % 3;
        wl[co][ci][SWAPW ? (dx * 3 + dy) : k] = wgt[i];
    }
    __syncthreads();

    const int x = tid & 63;
    const int cog = tid >> 6;

    float acc[4][8] = {};
    for (int ci = 0; ci < 16; ++ci) {
        float inr[10][3];
        #pragma unroll
        for (int yy = 0; yy < 10; ++yy) {
            inr[yy][0] = tin[ci][yy][x];
            inr[yy][1] = tin[ci][yy][x + 1];
            inr[yy][2] = tin[ci][yy][x + 2];
        }
        float wr[4][9];
        #pragma unroll
        for (int j = 0; j < 4; ++j)
            #pragma unroll
            for (int k = 0; k < 9; ++k) wr[j][k] = wl[cog * 4 + j][ci][k];
        #pragma unroll
        for (int j = 0; j < 4; ++j)
            #pragma unroll
            for (int dy = 0; dy < 3; ++dy)
                #pragma unroll
                for (int dx = 0; dx < 3; ++dx) {
                    const float w = wr[j][dy * 3 + dx];
                    #pragma unroll
                    for (int yy = 0; yy < 8; ++yy)
                        acc[j][yy] += inr[yy + dy][dx] * w;
                }
    }

    #pragma unroll
    for (int j = 0; j < 4; ++j) {
        const int co = cog * 4 + j;
        const size_t base = ((size_t)(b_ * 16 + co) * 81 + s_) * 4096;
        #pragma unroll
        for (int yy = 0; yy < 8; ++yy) {
            float vv = acc[j][yy];
            vv = (vv >= 0.f) ? vv : 0.2f * vv;
            const size_t idx = base + (size_t)(y0 + yy) * 64 + x;
            if (FINAL) vv += shortcut[idx];
            if (DSTB) outb[idx] = f2b(vv); else outf[idx] = vv;
        }
    }
}

extern "C" void kernel_launch(void* const* d_in, const int* in_sizes, int n_in,
                              void* d_out, int out_size, void* d_ws, size_t ws_size,
                              hipStream_t stream)
{
    const float* buffer = (const float*)d_in[0];
    const float* W_in   = (const float*)d_in[1];
    const float* ln1_g  = (const float*)d_in[2];
    const float* ln1_b  = (const float*)d_in[3];
    const float* W_qk   = (const float*)d_in[4];
    const float* W_v    = (const float*)d_in[5];
    const float* W_out  = (const float*)d_in[6];
    const float* ln2_g  = (const float*)d_in[7];
    const float* ln2_b  = (const float*)d_in[8];
    const float* W_ff1  = (const float*)d_in[9];
    const float* W_ff2  = (const float*)d_in[10];
    const float* W_lin  = (const float*)d_in[11];
    const float* cw1    = (const float*)d_in[12];
    const float* cw2    = (const float*)d_in[13];
    const float* cw3    = (const float*)d_in[14];

    // ws: [0, 85MB) bf16 activations; packed weights after.
    unsigned short* wsb = (unsigned short*)d_ws;
    unsigned short* pkw = (unsigned short*)((char*)d_ws + 84934656);

    const dim3 blk256(256);
    const dim3 tgrid(20736);
    const dim3 cgrid(8 * 81 * 8);

    pack_kernel<<<dim3(576), blk256, 0, stream>>>(W_in, W_qk, W_v, W_out, W_ff1, W_ff2, W_lin, pkw);

    // ---- pass 1 (all conv intermediates bf16; d_out used as bf16 scratch) ----
    trans_mfma<1, false><<<tgrid, blk256, 0, stream>>>(buffer, wsb, pkw, ln1_g, ln1_b, ln2_g, ln2_b);
    conv_kernel<true, true, false, false><<<cgrid, blk256, 0, stream>>>(wsb, d_out, cw1, nullptr);
    conv_kernel<true, true, false, false><<<cgrid, blk256, 0, stream>>>(d_out, wsb, cw2, nullptr);
    conv_kernel<true, true, false, true ><<<cgrid, blk256, 0, stream>>>(wsb, d_out, cw3, buffer);  // x1 bf16

    // ---- pass 2 ((h,w) order kept; conv taps transposed; final conv writes fp32) ----
    trans_mfma<2, true><<<tgrid, blk256, 0, stream>>>(d_out, wsb, pkw, ln1_g, ln1_b, ln2_g, ln2_b);
    conv_kernel<true, true, true, false><<<cgrid, blk256, 0, stream>>>(wsb, d_out, cw1, nullptr);
    conv_kernel<true, true, true, false><<<cgrid, blk256, 0, stream>>>(d_out, wsb, cw2, nullptr);
    conv_kernel<true, false, true, true><<<cgrid, blk256, 0, stream>>>(wsb, d_out, cw3, buffer);   // final fp32
}

// Round 6
// 1292.241 us; speedup vs baseline: 8.0698x; 1.6780x over previous
//
#include <hip/hip_runtime.h>
#include <cmath>

typedef float  f32x4_t  __attribute__((ext_vector_type(4)));
typedef short  bf16x8_t __attribute__((ext_vector_type(8)));

// R2-verified numerics primitives (manual RNE bf16 convert).
__device__ __forceinline__ unsigned short f2b(float f) {
    unsigned int u = __builtin_bit_cast(unsigned int, f);
    u += 0x7fffu + ((u >> 16) & 1u);          // RNE
    return (unsigned short)(u >> 16);
}
__device__ __forceinline__ unsigned int pk2(float lo, float hi) {
    return (unsigned int)f2b(lo) | ((unsigned int)f2b(hi) << 16);
}
__device__ __forceinline__ f32x4_t mfma16(bf16x8_t a, bf16x8_t b, f32x4_t c) {
    return __builtin_amdgcn_mfma_f32_16x16x32_bf16(a, b, c, 0, 0, 0);
}
__device__ __forceinline__ float gelu_f(float x) {   // exact erf gelu (R2-verified)
    return 0.5f * x * (1.f + erff(x * 0.70710678118654752f));
}
__device__ __forceinline__ float fexp(float v) {     // e^v, clamped to <= 0
    return expf(fminf(v, 0.f));
}

// ---------------- packed-weight layout (bf16 elements) ----------------
// pk[off + ((ct*KB + kb)*64 + lane)*8 + i] = W[kb*32+(lane>>4)*8+i][ct*16+(lane&15)]
// W_in rows and W_lin cols are PERMUTED: cin' = ph*32 + pw*16 + c  (c-contiguous)
#define PK_WIN   0        // 64x128,  KB=2
#define PK_WQK   8192     // 128x256, KB=4
#define PK_WV    40960    // 128x128, KB=4
#define PK_WOUT  57344    // 128x128, KB=4
#define PK_WFF1  73728    // 128x256, KB=4
#define PK_WFF2  106496   // 256x128, KB=8
#define PK_WLIN  139264   // 128x64,  KB=4
#define PK_TOTAL 147456

__global__ __launch_bounds__(256)
void pack_kernel(const float* __restrict__ W_in, const float* __restrict__ W_qk,
                 const float* __restrict__ W_v,  const float* __restrict__ W_out,
                 const float* __restrict__ W_ff1,const float* __restrict__ W_ff2,
                 const float* __restrict__ W_lin, unsigned short* __restrict__ pk)
{
    int i = blockIdx.x * 256 + threadIdx.x;
    if (i >= PK_TOTAL) return;
    const float* src; int N, off;
    if      (i < PK_WQK)  { src = W_in;  N = 128; off = PK_WIN;  }
    else if (i < PK_WV)   { src = W_qk;  N = 256; off = PK_WQK;  }
    else if (i < PK_WOUT) { src = W_v;   N = 128; off = PK_WV;   }
    else if (i < PK_WFF1) { src = W_out; N = 128; off = PK_WOUT; }
    else if (i < PK_WFF2) { src = W_ff1; N = 256; off = PK_WFF1; }
    else if (i < PK_WLIN) { src = W_ff2; N = 128; off = PK_WFF2; }
    else                  { src = W_lin; N = 64;  off = PK_WLIN; }
    int p = i - off;
    int ei = p & 7, lane = (p >> 3) & 63, rest = p >> 9;
    int KB = (off == PK_WIN) ? 2 : ((off == PK_WFF2) ? 8 : 4);
    int kb = rest % KB, ct = rest / KB;
    int k = kb * 32 + ((lane >> 4) << 3) + ei;
    int n = ct * 16 + (lane & 15);
    if (off == PK_WIN)  k = (k & 15) * 4 + ((k >> 5) & 1) * 2 + ((k >> 4) & 1);  // cin' -> cin
    if (off == PK_WLIN) n = (n & 15) * 4 + ((n >> 5) & 1) * 2 + ((n >> 4) & 1);
    pk[i] = f2b(src[k * N + n]);
}

// ---------------- trans LDS pool (44544 B -> 3 blocks/CU) ----------------
#define OFF_S1 16896
#define OFF_S2 25600
#define OFF_S3 35840
#define LDS_SZ 44544

// One block = one n, 4 waves. Activations pixel-major: [bs][y][x][ci16] bf16.
// PASS 1: h = 2t+ph, w = 2q+pw (src = fp32 c-major buffer).
// PASS 2: h = 2q+ph, w = 2t+pw (src = bf16 pixel-major x1).
template<int PASS>
__global__ __launch_bounds__(256, 3)
void trans_mfma(const void* __restrict__ src_, unsigned short* __restrict__ dst,
                const unsigned short* __restrict__ pk,
                const float* __restrict__ g1, const float* __restrict__ b1,
                const float* __restrict__ g2, const float* __restrict__ b2)
{
    __shared__ __align__(16) char POOL[LDS_SZ];
    float*          T   = (float*)POOL;                       // [32][132]
    unsigned short* xs  = (unsigned short*)(POOL + OFF_S1);   // [32][72]
    unsigned short* Tn  = (unsigned short*)(POOL + OFF_S1);   // [32][136]
    float*          Ssc = (float*)         (POOL + OFF_S1);   // [32][36]
    unsigned short* Ob  = (unsigned short*)(POOL + OFF_S1);   // [32][136]
    unsigned short* Q   = (unsigned short*)(POOL + OFF_S2);   // [32][136]
    unsigned short* Vt  = (unsigned short*)(POOL + OFF_S2);   // [128][40]
    unsigned short* FF  = (unsigned short*)(POOL + OFF_S2);   // [32][264]
    unsigned short* Km  = (unsigned short*)(POOL + OFF_S3);   // [32][136]
    unsigned short* Pp  = (unsigned short*)(POOL + OFF_S3);   // [32][40]

    const int tid  = threadIdx.x;
    const int lane = tid & 63;
    const int wv   = tid >> 6;
    const int lr   = lane & 15;
    const int lg   = lane >> 4;

    // XCD-bijective swizzle (20736 = 8*2592)
    const int bid = blockIdx.x;
    const int n = (bid & 7) * 2592 + (bid >> 3);
    const int q = n & 31;
    int r_ = n >> 5;
    const int v_ = r_ % 9; r_ /= 9;
    const int u_ = r_ % 9;
    const int b_ = r_ / 9;
    const int s_ = u_ * 9 + v_;
    const size_t plane = (size_t)(b_ * 16) * 81 + s_;     // c-major base (pass 1 / shortcuts)
    const size_t bs_pm = (size_t)(b_ * 81 + s_);          // pixel-major plane id

    auto ldA = [&](const unsigned short* buf, int stride, int rt, int kb) -> bf16x8_t {
        return *(const bf16x8_t*)(buf + (rt * 16 + lr) * stride + kb * 32 + lg * 8);
    };
    auto ldAf = [&](const float* buf, int stride, int rt, int kb) -> bf16x8_t {
        const float* p = buf + (rt * 16 + lr) * stride + kb * 32 + lg * 8;
        f32x4_t lo = *(const f32x4_t*)p, hi = *(const f32x4_t*)(p + 4);
        uint4 u;
        u.x = pk2(lo[0], lo[1]); u.y = pk2(lo[2], lo[3]);
        u.z = pk2(hi[0], hi[1]); u.w = pk2(hi[2], hi[3]);
        return __builtin_bit_cast(bf16x8_t, u);
    };
    auto ldB = [&](int base, int KB, int ct, int kb) -> bf16x8_t {
        return *(const bf16x8_t*)(pk + base + (((ct * KB + kb) * 64 + lane) << 3));
    };

    const float scale = 0.088388347648318447f;   // 1/sqrt(128)

    // ---- gather tokens -> xs bf16 [32][72], cin' = ph*32+pw*16+c ----
    if (PASS == 1) {
        const float* srcf = (const float*)src_;
        for (int i = tid; i < 1024; i += 256) {
            const int t = i >> 5, rest = i & 31;
            const int c = rest & 15, ph = rest >> 4;
            float2 f = *(const float2*)(srcf + (plane + (size_t)c * 81) * 4096
                                        + (2 * t + ph) * 64 + 2 * q);
            xs[t * 72 + ph * 32 + c]      = f2b(f.x);   // pw=0
            xs[t * 72 + ph * 32 + 16 + c] = f2b(f.y);   // pw=1
        }
    } else {
        const unsigned short* srcb = (const unsigned short*)src_;
        const int t = tid >> 3, rest = tid & 7;
        const int ch = rest & 1, pw = (rest >> 1) & 1, ph = rest >> 2;
        bf16x8_t v = *(const bf16x8_t*)(srcb + ((bs_pm * 64 + (2 * q + ph)) * 64
                                        + (2 * t + pw)) * 16 + ch * 8);
        *(bf16x8_t*)(xs + t * 72 + ph * 32 + pw * 16 + ch * 8) = v;
    }
    __syncthreads();

    // ---- G1: T = xs @ W_in (32x64x128) ----
    {
        const int ct0 = 2 * wv;
        bf16x8_t a[2][2], b[2][2];
        #pragma unroll
        for (int r = 0; r < 2; ++r) for (int k = 0; k < 2; ++k) a[r][k] = ldA(xs, 72, r, k);
        #pragma unroll
        for (int c = 0; c < 2; ++c) for (int k = 0; k < 2; ++k) b[c][k] = ldB(PK_WIN, 2, ct0 + c, k);
        #pragma unroll
        for (int r = 0; r < 2; ++r)
        #pragma unroll
        for (int c = 0; c < 2; ++c) {
            f32x4_t acc = {0.f, 0.f, 0.f, 0.f};
            acc = mfma16(a[r][0], b[c][0], acc);
            acc = mfma16(a[r][1], b[c][1], acc);
            const int col = (ct0 + c) * 16 + lr, r0 = r * 16 + lg * 4;
            #pragma unroll
            for (int i = 0; i < 4; ++i) T[(r0 + i) * 132 + col] = acc[i];
        }
    }
    __syncthreads();

    // ---- LN helper (vectorized loads, R2-verified convert) ----
    auto layernorm = [&](const float* g, const float* bb) {
        const int row = tid >> 3, sub = tid & 7;
        const float* tr = T + row * 132 + sub * 16;
        f32x4_t va = *(const f32x4_t*)tr,       vb = *(const f32x4_t*)(tr + 4),
                vc = *(const f32x4_t*)(tr + 8), vd = *(const f32x4_t*)(tr + 12);
        float sum = (va[0]+va[1]+va[2]+va[3]) + (vb[0]+vb[1]+vb[2]+vb[3])
                  + (vc[0]+vc[1]+vc[2]+vc[3]) + (vd[0]+vd[1]+vd[2]+vd[3]);
        #pragma unroll
        for (int m = 1; m < 8; m <<= 1) sum += __shfl_xor(sum, m, 8);
        const float mean = sum * (1.f / 128.f);
        float var = 0.f;
        #pragma unroll
        for (int i = 0; i < 4; ++i) { float d0=va[i]-mean, d1=vb[i]-mean, d2=vc[i]-mean, d3=vd[i]-mean;
                                      var += d0*d0 + d1*d1 + d2*d2 + d3*d3; }
        #pragma unroll
        for (int m = 1; m < 8; m <<= 1) var += __shfl_xor(var, m, 8);
        const float rstd = rsqrtf(var * (1.f / 128.f) + 1e-5f);
        const float* gp = g + sub * 16; const float* bp = bb + sub * 16;
        f32x4_t g0 = *(const f32x4_t*)gp,      g1v = *(const f32x4_t*)(gp + 4),
                g2v = *(const f32x4_t*)(gp+8), g3 = *(const f32x4_t*)(gp + 12);
        f32x4_t b0 = *(const f32x4_t*)bp,      b1v = *(const f32x4_t*)(bp + 4),
                b2v = *(const f32x4_t*)(bp+8), b3 = *(const f32x4_t*)(bp + 12);
        float o[16];
        #pragma unroll
        for (int i = 0; i < 4; ++i) {
            o[i]    = (va[i]-mean)*rstd*g0[i]  + b0[i];
            o[4+i]  = (vb[i]-mean)*rstd*g1v[i] + b1v[i];
            o[8+i]  = (vc[i]-mean)*rstd*g2v[i] + b2v[i];
            o[12+i] = (vd[i]-mean)*rstd*g3[i]  + b3[i];
        }
        uint4 u0, u1;
        u0.x = pk2(o[0],o[1]);   u0.y = pk2(o[2],o[3]);
        u0.z = pk2(o[4],o[5]);   u0.w = pk2(o[6],o[7]);
        u1.x = pk2(o[8],o[9]);   u1.y = pk2(o[10],o[11]);
        u1.z = pk2(o[12],o[13]); u1.w = pk2(o[14],o[15]);
        *(uint4*)(Tn + row * 136 + sub * 16)     = u0;
        *(uint4*)(Tn + row * 136 + sub * 16 + 8) = u1;
    };

    layernorm(g1, b1);
    __syncthreads();

    // ---- G2: [Q|K] = (Tn @ W_qk)*scale ----
    {
        bf16x8_t a[2][4];
        #pragma unroll
        for (int r = 0; r < 2; ++r) for (int k = 0; k < 4; ++k) a[r][k] = ldA(Tn, 136, r, k);
        #pragma unroll
        for (int h = 0; h < 2; ++h) {
            const int ct0 = h * 8 + 2 * wv;
            bf16x8_t b[2][4];
            #pragma unroll
            for (int c = 0; c < 2; ++c) for (int k = 0; k < 4; ++k) b[c][k] = ldB(PK_WQK, 4, ct0 + c, k);
            unsigned short* dsth = h ? Km : Q;
            #pragma unroll
            for (int r = 0; r < 2; ++r)
            #pragma unroll
            for (int c = 0; c < 2; ++c) {
                f32x4_t acc = {0.f, 0.f, 0.f, 0.f};
                #pragma unroll
                for (int k = 0; k < 4; ++k) acc = mfma16(a[r][k], b[c][k], acc);
                const int col = (ct0 + c - h * 8) * 16 + lr, r0 = r * 16 + lg * 4;
                #pragma unroll
                for (int i = 0; i < 4; ++i) dsth[(r0 + i) * 136 + col] = f2b(acc[i] * scale);
            }
        }
    }
    __syncthreads();

    // ---- scores: S = Q @ K^T ----
    {
        const int rt = wv & 1, ct = wv >> 1;
        bf16x8_t a[4], b[4];
        #pragma unroll
        for (int k = 0; k < 4; ++k) { a[k] = ldA(Q, 136, rt, k); b[k] = ldA(Km, 136, ct, k); }
        f32x4_t acc = {0.f, 0.f, 0.f, 0.f};
        #pragma unroll
        for (int k = 0; k < 4; ++k) acc = mfma16(a[k], b[k], acc);
        const int col = ct * 16 + lr, r0 = rt * 16 + lg * 4;
        #pragma unroll
        for (int i = 0; i < 4; ++i) Ssc[(r0 + i) * 36 + col] = acc[i];
    }
    __syncthreads();

    // ---- softmax -> Pp ; Wv: Vt = (T @ W_v)^T * scale ----
    {
        const int row = tid >> 3, sub = tid & 7;
        float v4[4]; float mx = -1e30f;
        #pragma unroll
        for (int i = 0; i < 4; ++i) { v4[i] = Ssc[row * 36 + sub * 4 + i]; mx = fmaxf(mx, v4[i]); }
        #pragma unroll
        for (int m = 1; m < 8; m <<= 1) mx = fmaxf(mx, __shfl_xor(mx, m, 8));
        float sm = 0.f;
        #pragma unroll
        for (int i = 0; i < 4; ++i) { v4[i] = fexp(v4[i] - mx); sm += v4[i]; }
        #pragma unroll
        for (int m = 1; m < 8; m <<= 1) sm += __shfl_xor(sm, m, 8);
        const float inv = 1.f / sm;
        uint2 pu;
        pu.x = pk2(v4[0] * inv, v4[1] * inv);
        pu.y = pk2(v4[2] * inv, v4[3] * inv);
        *(uint2*)(Pp + row * 40 + sub * 4) = pu;
    }
    {
        const int ct0 = 2 * wv;
        bf16x8_t b[2][4];
        #pragma unroll
        for (int c = 0; c < 2; ++c) for (int k = 0; k < 4; ++k) b[c][k] = ldB(PK_WV, 4, ct0 + c, k);
        #pragma unroll
        for (int r = 0; r < 2; ++r) {
            bf16x8_t a[4];
            #pragma unroll
            for (int k = 0; k < 4; ++k) a[k] = ldAf(T, 132, r, k);
            #pragma unroll
            for (int c = 0; c < 2; ++c) {
                f32x4_t acc = {0.f, 0.f, 0.f, 0.f};
                #pragma unroll
                for (int k = 0; k < 4; ++k) acc = mfma16(a[k], b[c][k], acc);
                const int col = (ct0 + c) * 16 + lr, r0 = r * 16 + lg * 4;
                uint2 vu;
                vu.x = pk2(acc[0] * scale, acc[1] * scale);
                vu.y = pk2(acc[2] * scale, acc[3] * scale);
                *(uint2*)(Vt + col * 40 + r0) = vu;   // transposed store
            }
        }
    }
    __syncthreads();

    // ---- PV: Ob = P @ V ----
    {
        const int ct0 = 2 * wv;
        bf16x8_t aa[2] = { ldA(Pp, 40, 0, 0), ldA(Pp, 40, 1, 0) };
        bf16x8_t bb[2] = { ldA(Vt, 40, ct0, 0), ldA(Vt, 40, ct0 + 1, 0) };
        #pragma unroll
        for (int r = 0; r < 2; ++r)
        #pragma unroll
        for (int c = 0; c < 2; ++c) {
            f32x4_t acc = {0.f, 0.f, 0.f, 0.f};
            acc = mfma16(aa[r], bb[c], acc);
            const int col = (ct0 + c) * 16 + lr, r0 = r * 16 + lg * 4;
            #pragma unroll
            for (int i = 0; i < 4; ++i) Ob[(r0 + i) * 136 + col] = f2b(acc[i]);
        }
    }
    __syncthreads();

    // ---- Wout: T += Ob @ W_out ----
    {
        const int ct0 = 2 * wv;
        bf16x8_t a[2][4], b[2][4];
        #pragma unroll
        for (int r = 0; r < 2; ++r) for (int k = 0; k < 4; ++k) a[r][k] = ldA(Ob, 136, r, k);
        #pragma unroll
        for (int c = 0; c < 2; ++c) for (int k = 0; k < 4; ++k) b[c][k] = ldB(PK_WOUT, 4, ct0 + c, k);
        #pragma unroll
        for (int r = 0; r < 2; ++r)
        #pragma unroll
        for (int c = 0; c < 2; ++c) {
            f32x4_t acc = {0.f, 0.f, 0.f, 0.f};
            #pragma unroll
            for (int k = 0; k < 4; ++k) acc = mfma16(a[r][k], b[c][k], acc);
            const int col = (ct0 + c) * 16 + lr, r0 = r * 16 + lg * 4;
            #pragma unroll
            for (int i = 0; i < 4; ++i) T[(r0 + i) * 132 + col] += acc[i];
        }
    }
    __syncthreads();

    layernorm(g2, b2);
    __syncthreads();

    // ---- ff1: FF = gelu(Tn @ W_ff1) ----
    {
        bf16x8_t a[2][4];
        #pragma unroll
        for (int r = 0; r < 2; ++r) for (int k = 0; k < 4; ++k) a[r][k] = ldA(Tn, 136, r, k);
        #pragma unroll
        for (int h = 0; h < 2; ++h) {
            const int ct0 = h * 8 + 2 * wv;
            bf16x8_t b[2][4];
            #pragma unroll
            for (int c = 0; c < 2; ++c) for (int k = 0; k < 4; ++k) b[c][k] = ldB(PK_WFF1, 4, ct0 + c, k);
            #pragma unroll
            for (int r = 0; r < 2; ++r)
            #pragma unroll
            for (int c = 0; c < 2; ++c) {
                f32x4_t acc = {0.f, 0.f, 0.f, 0.f};
                #pragma unroll
                for (int k = 0; k < 4; ++k) acc = mfma16(a[r][k], b[c][k], acc);
                const int col = (ct0 + c) * 16 + lr, r0 = r * 16 + lg * 4;
                #pragma unroll
                for (int i = 0; i < 4; ++i)
                    FF[(r0 + i) * 264 + col] = f2b(gelu_f(acc[i]));
            }
        }
    }
    __syncthreads();

    // ---- ff2: T += FF @ W_ff2 ----
    {
        const int ct0 = 2 * wv;
        f32x4_t acc[2][2] = {};
        #pragma unroll
        for (int half = 0; half < 2; ++half) {
            bf16x8_t a[2][4], b[2][4];
            #pragma unroll
            for (int r = 0; r < 2; ++r) for (int k = 0; k < 4; ++k) a[r][k] = ldA(FF, 264, r, half * 4 + k);
            #pragma unroll
            for (int c = 0; c < 2; ++c) for (int k = 0; k < 4; ++k) b[c][k] = ldB(PK_WFF2, 8, ct0 + c, half * 4 + k);
            #pragma unroll
            for (int r = 0; r < 2; ++r)
            #pragma unroll
            for (int c = 0; c < 2; ++c)
            #pragma unroll
            for (int k = 0; k < 4; ++k) acc[r][c] = mfma16(a[r][k], b[c][k], acc[r][c]);
        }
        #pragma unroll
        for (int r = 0; r < 2; ++r)
        #pragma unroll
        for (int c = 0; c < 2; ++c) {
            const int col = (ct0 + c) * 16 + lr, r0 = r * 16 + lg * 4;
            #pragma unroll
            for (int i = 0; i < 4; ++i) T[(r0 + i) * 132 + col] += acc[r][c][i];
        }
    }
    __syncthreads();

    // ---- Wlin: Y = T @ W_lin -> scatter pixel-major bf16 (cin' cols) ----
    {
        const int ct = wv;
        const int ph = ct >> 1, pw = ct & 1;
        bf16x8_t b[4];
        #pragma unroll
        for (int k = 0; k < 4; ++k) b[k] = ldB(PK_WLIN, 4, ct, k);
        #pragma unroll
        for (int r = 0; r < 2; ++r) {
            bf16x8_t a[4];
            #pragma unroll
            for (int k = 0; k < 4; ++k) a[k] = ldAf(T, 132, r, k);
            f32x4_t acc = {0.f, 0.f, 0.f, 0.f};
            #pragma unroll
            for (int k = 0; k < 4; ++k) acc = mfma16(a[k], b[k], acc);
            const int r0 = r * 16 + lg * 4;
            #pragma unroll
            for (int i = 0; i < 4; ++i) {
                const int t = r0 + i;
                size_t pix;
                if (PASS == 1) pix = (bs_pm * 64 + (2 * t + ph)) * 64 + (2 * q + pw);
                else           pix = (bs_pm * 64 + (2 * q + ph)) * 64 + (2 * t + pw);
                dst[pix * 16 + lr] = f2b(acc[i]);
            }
        }
    }
}

// ---------------- MFMA conv: 3x3, 16->16 ch, pad 1, leaky 0.2 ----------------
// input pixel-major bf16 [bs][y][x][ci16]; taps paired on K: k = (tap, ci).
// SWAPW: transpose taps. ADDSC: add fp32 c-major shortcut. F32OUT: final fp32 c-major.
template<bool SWAPW, bool ADDSC, bool F32OUT>
__global__ __launch_bounds__(256, 3)
void conv_mfma(const unsigned short* __restrict__ in, void* __restrict__ out_,
               const float* __restrict__ wgt, const float* __restrict__ shortcut)
{
    __shared__ unsigned short tin[18 * 66 * 16];   // 38016 B: rows -1..16, x-halo cols 0 & 65
    __shared__ unsigned short wpk[5 * 64 * 8];     // 5120 B: B-frags per kb

    const int tid = threadIdx.x, lane = tid & 63, wv = tid >> 6;
    const int lr = lane & 15, lg = lane >> 4;
    const int blk = blockIdx.x;
    const int yt = blk & 3, bs = blk >> 2;
    const int s_ = bs % 81, b_ = bs / 81;
    const int y0 = yt * 16;

    // zero x-halo
    for (int i = tid; i < 72; i += 256) {
        const int row = i >> 2, qh = i & 3;
        const int slot = (qh >> 1) ? 65 : 0, half = (qh & 1) * 8;
        *(bf16x8_t*)(tin + (row * 66 + slot) * 16 + half) = bf16x8_t{};
    }
    // stage 18 rows (contiguous copy, no transpose)
    for (int i = tid; i < 2304; i += 256) {
        const int row = i >> 7, c2 = i & 127, px = c2 >> 1, half = (c2 & 1) * 8;
        const int yg = y0 + row - 1;
        bf16x8_t v{};
        if (yg >= 0 && yg < 64)
            v = *(const bf16x8_t*)(in + ((size_t)(bs * 64 + yg) * 64 + px) * 16 + half);
        *(bf16x8_t*)(tin + (row * 66 + 1 + px) * 16 + half) = v;
    }
    // pack weights: wpk[(kb*64+ln)*8+e] = W[k=(ln>>4)*8+e (+32kb)][co=ln&15]
    for (int i = tid; i < 2560; i += 256) {
        const int kb = i >> 9, rest = i & 511, ln = rest >> 3, e = rest & 7;
        const int kl = ((ln >> 4) << 3) + e;
        const int tap = kb * 2 + (kl >> 4), ci = kl & 15, co = ln & 15;
        float w = 0.f;
        if (tap < 9) {
            const int tq = SWAPW ? (tap % 3) * 3 + tap / 3 : tap;
            w = wgt[(co * 16 + ci) * 9 + tq];
        }
        wpk[(kb * 64 + ln) * 8 + e] = f2b(w);
    }
    __syncthreads();

    const int xbase = wv * 16;     // wave owns one x-quadrant, sweeps y
    for (int y = 0; y < 16; ++y) {
        f32x4_t acc = {0.f, 0.f, 0.f, 0.f};
        #pragma unroll
        for (int kb = 0; kb < 5; ++kb) {
            int tap = kb * 2 + (lg >> 1); tap = tap > 8 ? 8 : tap;   // tap 9 -> zero weights
            const int dy = tap / 3, dxo = tap - dy * 3;
            const bf16x8_t a = *(const bf16x8_t*)(tin +
                ((y + dy) * 66 + xbase + lr + dxo) * 16 + (lg & 1) * 8);
            const bf16x8_t b = *(const bf16x8_t*)(wpk + (kb * 64 + lane) * 8);
            acc = mfma16(a, b, acc);
        }
        // C/D: col(lane&15)=co, rows lg*4+i = pixel x offset
        const int yg = y0 + y;
        const size_t cbase = ((size_t)(b_ * 16 + lr) * 81 + s_) * 4096
                           + (size_t)yg * 64 + xbase + lg * 4;   // c-major addr (sc/out)
        if (F32OUT) {
            float* outf = (float*)out_;
            f32x4_t r;
            if (ADDSC) {
                f32x4_t sc = *(const f32x4_t*)(shortcut + cbase);
                #pragma unroll
                for (int i = 0; i < 4; ++i) r[i] = fmaxf(acc[i], 0.2f * acc[i]) + sc[i];
            } else {
                #pragma unroll
                for (int i = 0; i < 4; ++i) r[i] = fmaxf(acc[i], 0.2f * acc[i]);
            }
            *(f32x4_t*)(outf + cbase) = r;
        } else {
            unsigned short* outb = (unsigned short*)out_;
            const size_t pbase = ((size_t)(bs * 64 + yg) * 64 + xbase + lg * 4) * 16 + lr;
            f32x4_t sc = {0.f, 0.f, 0.f, 0.f};
            if (ADDSC) sc = *(const f32x4_t*)(shortcut + cbase);
            #pragma unroll
            for (int i = 0; i < 4; ++i) {
                float v = fmaxf(acc[i], 0.2f * acc[i]) + sc[i];
                outb[pbase + (size_t)i * 16] = f2b(v);
            }
        }
    }
}

extern "C" void kernel_launch(void* const* d_in, const int* in_sizes, int n_in,
                              void* d_out, int out_size, void* d_ws, size_t ws_size,
                              hipStream_t stream)
{
    const float* buffer = (const float*)d_in[0];
    const float* W_in   = (const float*)d_in[1];
    const float* ln1_g  = (const float*)d_in[2];
    const float* ln1_b  = (const float*)d_in[3];
    const float* W_qk   = (const float*)d_in[4];
    const float* W_v    = (const float*)d_in[5];
    const float* W_out  = (const float*)d_in[6];
    const float* ln2_g  = (const float*)d_in[7];
    const float* ln2_b  = (const float*)d_in[8];
    const float* W_ff1  = (const float*)d_in[9];
    const float* W_ff2  = (const float*)d_in[10];
    const float* W_lin  = (const float*)d_in[11];
    const float* cw1    = (const float*)d_in[12];
    const float* cw2    = (const float*)d_in[13];
    const float* cw3    = (const float*)d_in[14];

    // A = ws[0:85MB) bf16 pixel-major; pk after. B = d_out reused as bf16 scratch.
    unsigned short* A   = (unsigned short*)d_ws;
    unsigned short* pkw = (unsigned short*)((char*)d_ws + 84934656);
    unsigned short* B   = (unsigned short*)d_out;

    const dim3 blk256(256);
    const dim3 tgrid(20736);
    const dim3 cgrid(648 * 4);

    pack_kernel<<<dim3(576), blk256, 0, stream>>>(W_in, W_qk, W_v, W_out, W_ff1, W_ff2, W_lin, pkw);

    // ---- pass 1 ----
    trans_mfma<1><<<tgrid, blk256, 0, stream>>>(buffer, A, pkw, ln1_g, ln1_b, ln2_g, ln2_b);
    conv_mfma<false, false, false><<<cgrid, blk256, 0, stream>>>(A, B, cw1, nullptr);
    conv_mfma<false, false, false><<<cgrid, blk256, 0, stream>>>(B, A, cw2, nullptr);
    conv_mfma<false, true,  false><<<cgrid, blk256, 0, stream>>>(A, B, cw3, buffer);   // x1 bf16 pm -> B

    // ---- pass 2 ((h,w) order kept; conv taps transposed) ----
    trans_mfma<2><<<tgrid, blk256, 0, stream>>>(B, A, pkw, ln1_g, ln1_b, ln2_g, ln2_b);
    conv_mfma<true, false, false><<<cgrid, blk256, 0, stream>>>(A, B, cw1, nullptr);
    conv_mfma<true, false, false><<<cgrid, blk256, 0, stream>>>(B, A, cw2, nullptr);
    conv_mfma<true, true,  true ><<<cgrid, blk256, 0, stream>>>(A, d_out, cw3, buffer); // final fp32
}

// Round 7
// 1268.725 us; speedup vs baseline: 8.2194x; 1.0185x over previous
//
#include <hip/hip_runtime.h>
#include <cmath>

typedef float  f32x4_t  __attribute__((ext_vector_type(4)));
typedef short  bf16x8_t __attribute__((ext_vector_type(8)));

// R2/R5-verified numerics primitives (manual RNE bf16 convert).
__device__ __forceinline__ unsigned short f2b(float f) {
    unsigned int u = __builtin_bit_cast(unsigned int, f);
    u += 0x7fffu + ((u >> 16) & 1u);          // RNE
    return (unsigned short)(u >> 16);
}
__device__ __forceinline__ unsigned int pk2(float lo, float hi) {
    return (unsigned int)f2b(lo) | ((unsigned int)f2b(hi) << 16);
}
__device__ __forceinline__ f32x4_t mfma16(bf16x8_t a, bf16x8_t b, f32x4_t c) {
    return __builtin_amdgcn_mfma_f32_16x16x32_bf16(a, b, c, 0, 0, 0);
}
// tanh-gelu, NaN-safe by construction: y clamped both sides, sigmoid in [0,1]
// computed BEFORE multiplying by x. |err| vs erf-gelu < ~1e-3.
__device__ __forceinline__ float gelu_f(float x) {
    float y2 = x * (1.5957691216057308f + 0.071354816222120564f * x * x);
    y2 = fmaxf(fminf(y2, 30.f), -30.f);
    float t = expf(y2);                       // libm expf (R5-verified path)
    return x * (t / (1.f + t));
}
__device__ __forceinline__ float fexp(float v) {     // e^v, clamped to <= 0
    return expf(fminf(v, 0.f));
}

// ---------------- packed-weight layout (bf16 elements) ----------------
// pk[off + ((ct*KB + kb)*64 + lane)*8 + i] = W[kb*32+(lane>>4)*8+i][ct*16+(lane&15)]
// W_in rows / W_lin cols PERMUTED: cin' = ph*32 + pw*16 + c.
// PK_M = (1/128) * Wq @ Wk^T (scores quadratic form); PK_WV pre-scaled by 1/sqrt(128).
#define PK_WIN   0        // 64x128,  KB=2
#define PK_M     8192     // 128x128, KB=4
#define PK_WV    24576    // 128x128, KB=4
#define PK_WOUT  40960    // 128x128, KB=4
#define PK_WFF1  57344    // 128x256, KB=4
#define PK_WFF2  90112    // 256x128, KB=8
#define PK_WLIN  122880   // 128x64,  KB=4
#define PK_TOTAL 131072

__global__ __launch_bounds__(256)
void pack_kernel(const float* __restrict__ W_in, const float* __restrict__ W_qk,
                 const float* __restrict__ W_v,  const float* __restrict__ W_out,
                 const float* __restrict__ W_ff1,const float* __restrict__ W_ff2,
                 const float* __restrict__ W_lin, unsigned short* __restrict__ pk)
{
    int i = blockIdx.x * 256 + threadIdx.x;
    if (i >= PK_TOTAL) return;
    const float* src = nullptr; int N = 0, off, KB;
    if      (i < PK_M)    { src = W_in;  N = 128; off = PK_WIN;  KB = 2; }
    else if (i < PK_WV)   {              N = 0;   off = PK_M;    KB = 4; }
    else if (i < PK_WOUT) { src = W_v;   N = 128; off = PK_WV;   KB = 4; }
    else if (i < PK_WFF1) { src = W_out; N = 128; off = PK_WOUT; KB = 4; }
    else if (i < PK_WFF2) { src = W_ff1; N = 256; off = PK_WFF1; KB = 4; }
    else if (i < PK_WLIN) { src = W_ff2; N = 128; off = PK_WFF2; KB = 8; }
    else                  { src = W_lin; N = 64;  off = PK_WLIN; KB = 4; }
    int p = i - off;
    int ei = p & 7, lane = (p >> 3) & 63, rest = p >> 9;
    int kb = rest % KB, ct = rest / KB;
    int k = kb * 32 + ((lane >> 4) << 3) + ei;
    int n = ct * 16 + (lane & 15);
    float v;
    if (off == PK_M) {
        // M[k][n] = (1/128) * sum_d W_qk[k][d] * W_qk[n][128+d]
        const f32x4_t* wq = (const f32x4_t*)(W_qk + k * 256);
        const f32x4_t* wk = (const f32x4_t*)(W_qk + n * 256 + 128);
        f32x4_t a4 = {0.f, 0.f, 0.f, 0.f};
        #pragma unroll
        for (int d = 0; d < 32; ++d) a4 += wq[d] * wk[d];
        v = (a4[0] + a4[1] + a4[2] + a4[3]) * (1.f / 128.f);
    } else {
        if (off == PK_WIN)  k = (k & 15) * 4 + ((k >> 5) & 1) * 2 + ((k >> 4) & 1);
        if (off == PK_WLIN) n = (n & 15) * 4 + ((n >> 5) & 1) * 2 + ((n >> 4) & 1);
        v = src[k * N + n];
        if (off == PK_WV) v *= 0.088388347648318447f;   // fold 1/sqrt(128)
    }
    pk[i] = f2b(v);
}

// ---------------- trans LDS pool (40960 B -> 4 blocks/CU) ----------------
// T   f32 [32][132] 16896 @ 0      (residual, live whole kernel)
// A   8704 @ 16896 : xs[32][72] | Tn[32][136] | Ob[32][136]
// B   8704 @ 25600 : U[32][136] | Vt[128][32] | FFh[32][136]
// Ssc f32 [32][36] 4608 @ 34304
// Pp  [32][32] 2048 @ 38912
#define OFF_A  16896
#define OFF_B  25600
#define OFF_C  34304
#define OFF_P  38912
#define LDS_SZ 40960

// One block = one n, 4 waves. Activations pixel-major: [bs][y][x][ci16] bf16.
// PASS 1: h = 2t+ph, w = 2q+pw (src = fp32 c-major buffer).
// PASS 2: h = 2q+ph, w = 2t+pw (src = bf16 pixel-major x1).
template<int PASS>
__global__ __launch_bounds__(256, 4)
void trans_mfma(const void* __restrict__ src_, unsigned short* __restrict__ dst,
                const unsigned short* __restrict__ pk,
                const float* __restrict__ g1, const float* __restrict__ b1,
                const float* __restrict__ g2, const float* __restrict__ b2)
{
    __shared__ __align__(16) char POOL[LDS_SZ];
    float*          T   = (float*)POOL;                       // [32][132]
    unsigned short* xs  = (unsigned short*)(POOL + OFF_A);    // [32][72]
    unsigned short* Tn  = (unsigned short*)(POOL + OFF_A);    // [32][136]
    unsigned short* Ob  = (unsigned short*)(POOL + OFF_A);    // [32][136]
    unsigned short* U   = (unsigned short*)(POOL + OFF_B);    // [32][136]
    unsigned short* Vt  = (unsigned short*)(POOL + OFF_B);    // [128][32]
    unsigned short* FFh = (unsigned short*)(POOL + OFF_B);    // [32][136]
    float*          Ssc = (float*)         (POOL + OFF_C);    // [32][36]
    unsigned short* Pp  = (unsigned short*)(POOL + OFF_P);    // [32][32]

    const int tid  = threadIdx.x;
    const int lane = tid & 63;
    const int wv   = tid >> 6;
    const int lr   = lane & 15;
    const int lg   = lane >> 4;

    // XCD-bijective swizzle (20736 = 8*2592)
    const int bid = blockIdx.x;
    const int n = (bid & 7) * 2592 + (bid >> 3);
    const int q = n & 31;
    int r_ = n >> 5;
    const int v_ = r_ % 9; r_ /= 9;
    const int u_ = r_ % 9;
    const int b_ = r_ / 9;
    const int s_ = u_ * 9 + v_;
    const size_t plane = (size_t)(b_ * 16) * 81 + s_;     // c-major base (pass 1)
    const size_t bs_pm = (size_t)(b_ * 81 + s_);          // pixel-major plane id

    auto ldA = [&](const unsigned short* buf, int stride, int rt, int kb) -> bf16x8_t {
        return *(const bf16x8_t*)(buf + (rt * 16 + lr) * stride + kb * 32 + lg * 8);
    };
    auto ldAf = [&](const float* buf, int stride, int rt, int kb) -> bf16x8_t {
        const float* p = buf + (rt * 16 + lr) * stride + kb * 32 + lg * 8;
        f32x4_t lo = *(const f32x4_t*)p, hi = *(const f32x4_t*)(p + 4);
        uint4 u;
        u.x = pk2(lo[0], lo[1]); u.y = pk2(lo[2], lo[3]);
        u.z = pk2(hi[0], hi[1]); u.w = pk2(hi[2], hi[3]);
        return __builtin_bit_cast(bf16x8_t, u);
    };
    auto ldB = [&](int base, int KB, int ct, int kb) -> bf16x8_t {
        return *(const bf16x8_t*)(pk + base + (((ct * KB + kb) * 64 + lane) << 3));
    };

    // ---- gather tokens -> xs bf16 [32][72], cin' = ph*32+pw*16+c ----
    if (PASS == 1) {
        const float* srcf = (const float*)src_;
        for (int i = tid; i < 1024; i += 256) {
            const int t = i >> 5, rest = i & 31;
            const int c = rest & 15, ph = rest >> 4;
            float2 f = *(const float2*)(srcf + (plane + (size_t)c * 81) * 4096
                                        + (2 * t + ph) * 64 + 2 * q);
            xs[t * 72 + ph * 32 + c]      = f2b(f.x);   // pw=0
            xs[t * 72 + ph * 32 + 16 + c] = f2b(f.y);   // pw=1
        }
    } else {
        const unsigned short* srcb = (const unsigned short*)src_;
        const int t = tid >> 3, rest = tid & 7;
        const int ch = rest & 1, pw = (rest >> 1) & 1, ph = rest >> 2;
        bf16x8_t v = *(const bf16x8_t*)(srcb + ((bs_pm * 64 + (2 * q + ph)) * 64
                                        + (2 * t + pw)) * 16 + ch * 8);
        *(bf16x8_t*)(xs + t * 72 + ph * 32 + pw * 16 + ch * 8) = v;
    }
    __syncthreads();

    // ---- G1: T = xs @ W_in (32x64x128) ----
    {
        const int ct0 = 2 * wv;
        bf16x8_t a[2][2], b[2][2];
        #pragma unroll
        for (int r = 0; r < 2; ++r) for (int k = 0; k < 2; ++k) a[r][k] = ldA(xs, 72, r, k);
        #pragma unroll
        for (int c = 0; c < 2; ++c) for (int k = 0; k < 2; ++k) b[c][k] = ldB(PK_WIN, 2, ct0 + c, k);
        #pragma unroll
        for (int r = 0; r < 2; ++r)
        #pragma unroll
        for (int c = 0; c < 2; ++c) {
            f32x4_t acc = {0.f, 0.f, 0.f, 0.f};
            acc = mfma16(a[r][0], b[c][0], acc);
            acc = mfma16(a[r][1], b[c][1], acc);
            const int col = (ct0 + c) * 16 + lr, r0 = r * 16 + lg * 4;
            #pragma unroll
            for (int i = 0; i < 4; ++i) T[(r0 + i) * 132 + col] = acc[i];
        }
    }
    __syncthreads();

    // ---- LN helper ----
    auto layernorm = [&](const float* g, const float* bb) {
        const int row = tid >> 3, sub = tid & 7;
        const float* tr = T + row * 132 + sub * 16;
        f32x4_t va = *(const f32x4_t*)tr,       vb = *(const f32x4_t*)(tr + 4),
                vc = *(const f32x4_t*)(tr + 8), vd = *(const f32x4_t*)(tr + 12);
        float sum = (va[0]+va[1]+va[2]+va[3]) + (vb[0]+vb[1]+vb[2]+vb[3])
                  + (vc[0]+vc[1]+vc[2]+vc[3]) + (vd[0]+vd[1]+vd[2]+vd[3]);
        #pragma unroll
        for (int m = 1; m < 8; m <<= 1) sum += __shfl_xor(sum, m, 8);
        const float mean = sum * (1.f / 128.f);
        float var = 0.f;
        #pragma unroll
        for (int i = 0; i < 4; ++i) { float d0=va[i]-mean, d1=vb[i]-mean, d2=vc[i]-mean, d3=vd[i]-mean;
                                      var += d0*d0 + d1*d1 + d2*d2 + d3*d3; }
        #pragma unroll
        for (int m = 1; m < 8; m <<= 1) var += __shfl_xor(var, m, 8);
        const float rstd = rsqrtf(var * (1.f / 128.f) + 1e-5f);
        const float* gp = g + sub * 16; const float* bp = bb + sub * 16;
        f32x4_t g0 = *(const f32x4_t*)gp,      g1v = *(const f32x4_t*)(gp + 4),
                g2v = *(const f32x4_t*)(gp+8), g3 = *(const f32x4_t*)(gp + 12);
        f32x4_t b0 = *(const f32x4_t*)bp,      b1v = *(const f32x4_t*)(bp + 4),
                b2v = *(const f32x4_t*)(bp+8), b3 = *(const f32x4_t*)(bp + 12);
        float o[16];
        #pragma unroll
        for (int i = 0; i < 4; ++i) {
            o[i]    = (va[i]-mean)*rstd*g0[i]  + b0[i];
            o[4+i]  = (vb[i]-mean)*rstd*g1v[i] + b1v[i];
            o[8+i]  = (vc[i]-mean)*rstd*g2v[i] + b2v[i];
            o[12+i] = (vd[i]-mean)*rstd*g3[i]  + b3[i];
        }
        uint4 u0, u1;
        u0.x = pk2(o[0],o[1]);   u0.y = pk2(o[2],o[3]);
        u0.z = pk2(o[4],o[5]);   u0.w = pk2(o[6],o[7]);
        u1.x = pk2(o[8],o[9]);   u1.y = pk2(o[10],o[11]);
        u1.z = pk2(o[12],o[13]); u1.w = pk2(o[14],o[15]);
        *(uint4*)(Tn + row * 136 + sub * 16)     = u0;
        *(uint4*)(Tn + row * 136 + sub * 16 + 8) = u1;
    };

    layernorm(g1, b1);
    __syncthreads();

    // ---- U = Tn @ M (32x128x128); M pre-scaled by 1/128 ----
    {
        const int ct0 = 2 * wv;
        bf16x8_t a[2][4], b[2][4];
        #pragma unroll
        for (int r = 0; r < 2; ++r) for (int k = 0; k < 4; ++k) a[r][k] = ldA(Tn, 136, r, k);
        #pragma unroll
        for (int c = 0; c < 2; ++c) for (int k = 0; k < 4; ++k) b[c][k] = ldB(PK_M, 4, ct0 + c, k);
        #pragma unroll
        for (int r = 0; r < 2; ++r)
        #pragma unroll
        for (int c = 0; c < 2; ++c) {
            f32x4_t acc = {0.f, 0.f, 0.f, 0.f};
            #pragma unroll
            for (int k = 0; k < 4; ++k) acc = mfma16(a[r][k], b[c][k], acc);
            const int col = (ct0 + c) * 16 + lr, r0 = r * 16 + lg * 4;
            #pragma unroll
            for (int i = 0; i < 4; ++i) U[(r0 + i) * 136 + col] = f2b(acc[i]);
        }
    }
    __syncthreads();

    // ---- scores: S = U @ Tn^T (32x128x32) ----
    {
        const int rt = wv & 1, ct = wv >> 1;
        bf16x8_t a[4], b[4];
        #pragma unroll
        for (int k = 0; k < 4; ++k) { a[k] = ldA(U, 136, rt, k); b[k] = ldA(Tn, 136, ct, k); }
        f32x4_t acc = {0.f, 0.f, 0.f, 0.f};
        #pragma unroll
        for (int k = 0; k < 4; ++k) acc = mfma16(a[k], b[k], acc);
        const int col = ct * 16 + lr, r0 = rt * 16 + lg * 4;
        #pragma unroll
        for (int i = 0; i < 4; ++i) Ssc[(r0 + i) * 36 + col] = acc[i];
    }
    __syncthreads();

    // ---- softmax -> Pp ; Wv: Vt = (T @ Wv*scale)^T ----
    {
        const int row = tid >> 3, sub = tid & 7;
        float v4[4]; float mx = -1e30f;
        #pragma unroll
        for (int i = 0; i < 4; ++i) { v4[i] = Ssc[row * 36 + sub * 4 + i]; mx = fmaxf(mx, v4[i]); }
        #pragma unroll
        for (int m = 1; m < 8; m <<= 1) mx = fmaxf(mx, __shfl_xor(mx, m, 8));
        float sm = 0.f;
        #pragma unroll
        for (int i = 0; i < 4; ++i) { v4[i] = fexp(v4[i] - mx); sm += v4[i]; }
        #pragma unroll
        for (int m = 1; m < 8; m <<= 1) sm += __shfl_xor(sm, m, 8);
        const float inv = 1.f / sm;
        uint2 pu;
        pu.x = pk2(v4[0] * inv, v4[1] * inv);
        pu.y = pk2(v4[2] * inv, v4[3] * inv);
        *(uint2*)(Pp + row * 32 + sub * 4) = pu;
    }
    {
        const int ct0 = 2 * wv;
        bf16x8_t b[2][4];
        #pragma unroll
        for (int c = 0; c < 2; ++c) for (int k = 0; k < 4; ++k) b[c][k] = ldB(PK_WV, 4, ct0 + c, k);
        #pragma unroll
        for (int r = 0; r < 2; ++r) {
            bf16x8_t a[4];
            #pragma unroll
            for (int k = 0; k < 4; ++k) a[k] = ldAf(T, 132, r, k);
            #pragma unroll
            for (int c = 0; c < 2; ++c) {
                f32x4_t acc = {0.f, 0.f, 0.f, 0.f};
                #pragma unroll
                for (int k = 0; k < 4; ++k) acc = mfma16(a[k], b[c][k], acc);
                const int col = (ct0 + c) * 16 + lr, r0 = r * 16 + lg * 4;
                uint2 vu;
                vu.x = pk2(acc[0], acc[1]);
                vu.y = pk2(acc[2], acc[3]);
                *(uint2*)(Vt + col * 32 + r0) = vu;   // transposed store
            }
        }
    }
    __syncthreads();

    // ---- PV: Ob = P @ V (32x32x128) ----
    {
        const int ct0 = 2 * wv;
        bf16x8_t aa[2] = { ldA(Pp, 32, 0, 0), ldA(Pp, 32, 1, 0) };
        bf16x8_t bb[2] = { ldA(Vt, 32, ct0, 0), ldA(Vt, 32, ct0 + 1, 0) };
        #pragma unroll
        for (int r = 0; r < 2; ++r)
        #pragma unroll
        for (int c = 0; c < 2; ++c) {
            f32x4_t acc = {0.f, 0.f, 0.f, 0.f};
            acc = mfma16(aa[r], bb[c], acc);
            const int col = (ct0 + c) * 16 + lr, r0 = r * 16 + lg * 4;
            #pragma unroll
            for (int i = 0; i < 4; ++i) Ob[(r0 + i) * 136 + col] = f2b(acc[i]);
        }
    }
    __syncthreads();

    // ---- Wout: T += Ob @ W_out ----
    {
        const int ct0 = 2 * wv;
        bf16x8_t a[2][4], b[2][4];
        #pragma unroll
        for (int r = 0; r < 2; ++r) for (int k = 0; k < 4; ++k) a[r][k] = ldA(Ob, 136, r, k);
        #pragma unroll
        for (int c = 0; c < 2; ++c) for (int k = 0; k < 4; ++k) b[c][k] = ldB(PK_WOUT, 4, ct0 + c, k);
        #pragma unroll
        for (int r = 0; r < 2; ++r)
        #pragma unroll
        for (int c = 0; c < 2; ++c) {
            f32x4_t acc = {0.f, 0.f, 0.f, 0.f};
            #pragma unroll
            for (int k = 0; k < 4; ++k) acc = mfma16(a[r][k], b[c][k], acc);
            const int col = (ct0 + c) * 16 + lr, r0 = r * 16 + lg * 4;
            #pragma unroll
            for (int i = 0; i < 4; ++i) T[(r0 + i) * 132 + col] += acc[i];
        }
    }
    __syncthreads();

    layernorm(g2, b2);
    __syncthreads();

    // ---- ff: two 128-col halves, FF buffer halved, ff2 acc in registers ----
    {
        const int ct0 = 2 * wv;
        f32x4_t fac[2][2] = {};
        #pragma unroll
        for (int h = 0; h < 2; ++h) {
            {   // ff1 half: FFh = gelu(Tn @ Wff1[:, h*128:])
                bf16x8_t a[2][4], b[2][4];
                #pragma unroll
                for (int r = 0; r < 2; ++r) for (int k = 0; k < 4; ++k) a[r][k] = ldA(Tn, 136, r, k);
                const int cth = h * 8 + ct0;
                #pragma unroll
                for (int c = 0; c < 2; ++c) for (int k = 0; k < 4; ++k) b[c][k] = ldB(PK_WFF1, 4, cth + c, k);
                #pragma unroll
                for (int r = 0; r < 2; ++r)
                #pragma unroll
                for (int c = 0; c < 2; ++c) {
                    f32x4_t acc = {0.f, 0.f, 0.f, 0.f};
                    #pragma unroll
                    for (int k = 0; k < 4; ++k) acc = mfma16(a[r][k], b[c][k], acc);
                    const int col = (ct0 + c) * 16 + lr, r0 = r * 16 + lg * 4;
                    #pragma unroll
                    for (int i = 0; i < 4; ++i)
                        FFh[(r0 + i) * 136 + col] = f2b(gelu_f(acc[i]));
                }
            }
            __syncthreads();
            {   // ff2 half: fac += FFh @ Wff2[h*128:,:]
                bf16x8_t a[2][4], b[2][4];
                #pragma unroll
                for (int r = 0; r < 2; ++r) for (int k = 0; k < 4; ++k) a[r][k] = ldA(FFh, 136, r, k);
                #pragma unroll
                for (int c = 0; c < 2; ++c) for (int k = 0; k < 4; ++k) b[c][k] = ldB(PK_WFF2, 8, ct0 + c, h * 4 + k);
                #pragma unroll
                for (int r = 0; r < 2; ++r)
                #pragma unroll
                for (int c = 0; c < 2; ++c)
                #pragma unroll
                for (int k = 0; k < 4; ++k) fac[r][c] = mfma16(a[r][k], b[c][k], fac[r][c]);
            }
            __syncthreads();
        }
        #pragma unroll
        for (int r = 0; r < 2; ++r)
        #pragma unroll
        for (int c = 0; c < 2; ++c) {
            const int col = (ct0 + c) * 16 + lr, r0 = r * 16 + lg * 4;
            #pragma unroll
            for (int i = 0; i < 4; ++i) T[(r0 + i) * 132 + col] += fac[r][c][i];
        }
    }
    __syncthreads();

    // ---- Wlin: Y = T @ W_lin -> scatter pixel-major bf16 (cin' cols) ----
    {
        const int ct = wv;
        const int ph = ct >> 1, pw = ct & 1;
        bf16x8_t b[4];
        #pragma unroll
        for (int k = 0; k < 4; ++k) b[k] = ldB(PK_WLIN, 4, ct, k);
        #pragma unroll
        for (int r = 0; r < 2; ++r) {
            bf16x8_t a[4];
            #pragma unroll
            for (int k = 0; k < 4; ++k) a[k] = ldAf(T, 132, r, k);
            f32x4_t acc = {0.f, 0.f, 0.f, 0.f};
            #pragma unroll
            for (int k = 0; k < 4; ++k) acc = mfma16(a[k], b[k], acc);
            const int r0 = r * 16 + lg * 4;
            #pragma unroll
            for (int i = 0; i < 4; ++i) {
                const int t = r0 + i;
                size_t pix;
                if (PASS == 1) pix = (bs_pm * 64 + (2 * t + ph)) * 64 + (2 * q + pw);
                else           pix = (bs_pm * 64 + (2 * q + ph)) * 64 + (2 * t + pw);
                dst[pix * 16 + lr] = f2b(acc[i]);
            }
        }
    }
}

// ---------------- MFMA conv: 3x3, 16->16 ch, pad 1, leaky 0.2 (R5-verified) ----
template<bool SWAPW, bool ADDSC, bool F32OUT>
__global__ __launch_bounds__(256, 3)
void conv_mfma(const unsigned short* __restrict__ in, void* __restrict__ out_,
               const float* __restrict__ wgt, const float* __restrict__ shortcut)
{
    __shared__ unsigned short tin[18 * 66 * 16];   // rows -1..16, x-halo cols 0 & 65
    __shared__ unsigned short wpk[5 * 64 * 8];

    const int tid = threadIdx.x, lane = tid & 63, wv = tid >> 6;
    const int lr = lane & 15, lg = lane >> 4;
    const int blk = blockIdx.x;
    const int yt = blk & 3, bs = blk >> 2;
    const int s_ = bs % 81, b_ = bs / 81;
    const int y0 = yt * 16;

    for (int i = tid; i < 72; i += 256) {
        const int row = i >> 2, qh = i & 3;
        const int slot = (qh >> 1) ? 65 : 0, half = (qh & 1) * 8;
        *(bf16x8_t*)(tin + (row * 66 + slot) * 16 + half) = bf16x8_t{};
    }
    for (int i = tid; i < 2304; i += 256) {
        const int row = i >> 7, c2 = i & 127, px = c2 >> 1, half = (c2 & 1) * 8;
        const int yg = y0 + row - 1;
        bf16x8_t v{};
        if (yg >= 0 && yg < 64)
            v = *(const bf16x8_t*)(in + ((size_t)(bs * 64 + yg) * 64 + px) * 16 + half);
        *(bf16x8_t*)(tin + (row * 66 + 1 + px) * 16 + half) = v;
    }
    for (int i = tid; i < 2560; i += 256) {
        const int kb = i >> 9, rest = i & 511, ln = rest >> 3, e = rest & 7;
        const int kl = ((ln >> 4) << 3) + e;
        const int tap = kb * 2 + (kl >> 4), ci = kl & 15, co = ln & 15;
        float w = 0.f;
        if (tap < 9) {
            const int tq = SWAPW ? (tap % 3) * 3 + tap / 3 : tap;
            w = wgt[(co * 16 + ci) * 9 + tq];
        }
        wpk[(kb * 64 + ln) * 8 + e] = f2b(w);
    }
    __syncthreads();

    const int xbase = wv * 16;
    for (int y = 0; y < 16; ++y) {
        f32x4_t acc = {0.f, 0.f, 0.f, 0.f};
        #pragma unroll
        for (int kb = 0; kb < 5; ++kb) {
            int tap = kb * 2 + (lg >> 1); tap = tap > 8 ? 8 : tap;
            const int dy = tap / 3, dxo = tap - dy * 3;
            const bf16x8_t a = *(const bf16x8_t*)(tin +
                ((y + dy) * 66 + xbase + lr + dxo) * 16 + (lg & 1) * 8);
            const bf16x8_t b = *(const bf16x8_t*)(wpk + (kb * 64 + lane) * 8);
            acc = mfma16(a, b, acc);
        }
        const int yg = y0 + y;
        const size_t cbase = ((size_t)(b_ * 16 + lr) * 81 + s_) * 4096
                           + (size_t)yg * 64 + xbase + lg * 4;
        if (F32OUT) {
            float* outf = (float*)out_;
            f32x4_t r;
            if (ADDSC) {
                f32x4_t sc = *(const f32x4_t*)(shortcut + cbase);
                #pragma unroll
                for (int i = 0; i < 4; ++i) r[i] = fmaxf(acc[i], 0.2f * acc[i]) + sc[i];
            } else {
                #pragma unroll
                for (int i = 0; i < 4; ++i) r[i] = fmaxf(acc[i], 0.2f * acc[i]);
            }
            *(f32x4_t*)(outf + cbase) = r;
        } else {
            unsigned short* outb = (unsigned short*)out_;
            const size_t pbase = ((size_t)(bs * 64 + yg) * 64 + xbase + lg * 4) * 16 + lr;
            f32x4_t sc = {0.f, 0.f, 0.f, 0.f};
            if (ADDSC) sc = *(const f32x4_t*)(shortcut + cbase);
            #pragma unroll
            for (int i = 0; i < 4; ++i) {
                float v = fmaxf(acc[i], 0.2f * acc[i]) + sc[i];
                outb[pbase + (size_t)i * 16] = f2b(v);
            }
        }
    }
}

extern "C" void kernel_launch(void* const* d_in, const int* in_sizes, int n_in,
                              void* d_out, int out_size, void* d_ws, size_t ws_size,
                              hipStream_t stream)
{
    const float* buffer = (const float*)d_in[0];
    const float* W_in   = (const float*)d_in[1];
    const float* ln1_g  = (const float*)d_in[2];
    const float* ln1_b  = (const float*)d_in[3];
    const float* W_qk   = (const float*)d_in[4];
    const float* W_v    = (const float*)d_in[5];
    const float* W_out  = (const float*)d_in[6];
    const float* ln2_g  = (const float*)d_in[7];
    const float* ln2_b  = (const float*)d_in[8];
    const float* W_ff1  = (const float*)d_in[9];
    const float* W_ff2  = (const float*)d_in[10];
    const float* W_lin  = (const float*)d_in[11];
    const float* cw1    = (const float*)d_in[12];
    const float* cw2    = (const float*)d_in[13];
    const float* cw3    = (const float*)d_in[14];

    // A = ws[0:85MB) bf16 pixel-major; pk after. B = d_out reused as bf16 scratch.
    unsigned short* A   = (unsigned short*)d_ws;
    unsigned short* pkw = (unsigned short*)((char*)d_ws + 84934656);
    unsigned short* B   = (unsigned short*)d_out;

    const dim3 blk256(256);
    const dim3 tgrid(20736);
    const dim3 cgrid(648 * 4);

    pack_kernel<<<dim3(512), blk256, 0, stream>>>(W_in, W_qk, W_v, W_out, W_ff1, W_ff2, W_lin, pkw);

    // ---- pass 1 ----
    trans_mfma<1><<<tgrid, blk256, 0, stream>>>(buffer, A, pkw, ln1_g, ln1_b, ln2_g, ln2_b);
    conv_mfma<false, false, false><<<cgrid, blk256, 0, stream>>>(A, B, cw1, nullptr);
    conv_mfma<false, false, false><<<cgrid, blk256, 0, stream>>>(B, A, cw2, nullptr);
    conv_mfma<false, true,  false><<<cgrid, blk256, 0, stream>>>(A, B, cw3, buffer);   // x1 bf16 pm -> B

    // ---- pass 2 ((h,w) order kept; conv taps transposed) ----
    trans_mfma<2><<<tgrid, blk256, 0, stream>>>(B, A, pkw, ln1_g, ln1_b, ln2_g, ln2_b);
    conv_mfma<true, false, false><<<cgrid, blk256, 0, stream>>>(A, B, cw1, nullptr);
    conv_mfma<true, false, false><<<cgrid, blk256, 0, stream>>>(B, A, cw2, nullptr);
    conv_mfma<true, true,  true ><<<cgrid, blk256, 0, stream>>>(A, d_out, cw3, buffer); // final fp32
}